// Round 3
// baseline (9395.212 us; speedup 1.0000x reference)
//
#include <hip/hip_runtime.h>
#include <float.h>
#include <math.h>

#define NPT 2048        // points per batch
#define NBATCH 8
#define NPTS_TOTAL 16384
#define KNN 10
#define STAT_BLOCKS 1024

// ---------------- transpose (S,B,K,D) -> pts[b*2048+n][24] ----------------
__global__ __launch_bounds__(256) void k_pts(const float* __restrict__ x, float* __restrict__ pts) {
    int i = blockIdx.x * 256 + threadIdx.x;
    if (i >= NPTS_TOTAL * 24) return;
    int p = i / 24, c = i - p * 24;
    int b = p >> 11, n = p & 2047;
    pts[i] = x[(n * 8 + b) * 24 + c];
}

// ---------------- per-point squared norms in f64 ----------------
__global__ __launch_bounds__(256) void k_norm(const float* __restrict__ x, int ld, int C,
                                              double* __restrict__ norms) {
    int p = blockIdx.x * 256 + threadIdx.x;
    if (p >= NPTS_TOTAL) return;
    const float* row = x + (size_t)p * ld;
    double s = 0.0;
    for (int c = 0; c < C; ++c) { double v = (double)row[c]; s += v * v; }
    norms[p] = s;
}

// ---------------- KNN: one block per point, f64 distances ----------------
template<int C4>
__global__ __launch_bounds__(256) void k_knn(const float* __restrict__ x, int ld,
                                             const double* __restrict__ norms,
                                             int* __restrict__ idx_out) {
    __shared__ double dist[NPT];
    __shared__ float4 sctr[C4];
    __shared__ double bval[4];
    __shared__ int    bidx[4];
    int p = blockIdx.x;
    int b = p >> 11, n = p & 2047;
    const float* xb = x + (size_t)b * NPT * ld;
    const double* nb = norms + (size_t)b * NPT;
    int tid = threadIdx.x;
    if (tid < C4) sctr[tid] = ((const float4*)(xb + (size_t)n * ld))[tid];
    __syncthreads();
    double nn = nb[n];
    for (int m = tid; m < NPT; m += 256) {
        const float4* xm = (const float4*)(xb + (size_t)m * ld);
        double dot = 0.0;
#pragma unroll
        for (int c = 0; c < C4; ++c) {
            float4 v = xm[c], u = sctr[c];
            dot += (double)u.x * (double)v.x + (double)u.y * (double)v.y
                 + (double)u.z * (double)v.z + (double)u.w * (double)v.w;
        }
        dist[m] = 2.0 * dot - nn - nb[m];   // = -|xn-xm|^2 ; self ~ 0 (max)
    }
    __syncthreads();
    for (int t = 0; t < KNN; ++t) {
        double best = -DBL_MAX; int bi = 0x7fffffff;
        for (int m = tid; m < NPT; m += 256) {
            double v = dist[m];
            if (v > best || (v == best && m < bi)) { best = v; bi = m; }
        }
#pragma unroll
        for (int off = 32; off > 0; off >>= 1) {
            double ov = __shfl_down(best, off);
            int    oi = __shfl_down(bi, off);
            if (ov > best || (ov == best && oi < bi)) { best = ov; bi = oi; }
        }
        if ((tid & 63) == 0) { bval[tid >> 6] = best; bidx[tid >> 6] = bi; }
        __syncthreads();
        if (tid == 0) {
            double bb = bval[0]; int ii = bidx[0];
            for (int w = 1; w < 4; ++w)
                if (bval[w] > bb || (bval[w] == bb && bidx[w] < ii)) { bb = bval[w]; ii = bidx[w]; }
            idx_out[p * KNN + t] = ii;
            dist[ii] = -DBL_MAX;
        }
        __syncthreads();
    }
}

// ---------------- edgeconv (two-pass) ----------------
// h[k][o] = W[o][0:C]·nb_k + (W[o][C:2C]-W[o][0:C])·ctr
// PASS 0: per-block partial sum/sumsq of h per channel (f64, deterministic).
// PASS 1: out = max_k leaky(h*sc+sh)
template<int PASS, int C, int O>
__global__ __launch_bounds__(256) void k_conv(const float* __restrict__ x, int ld,
                                              const int* __restrict__ idx,
                                              const float* __restrict__ W,
                                              double* __restrict__ partials,
                                              const float* __restrict__ ss,
                                              float* __restrict__ out, int ldo) {
    const int PTS = 16;
    __shared__ float sctr[C];
    __shared__ float snb[KNN * C];
    __shared__ int sidx[KNN];
    int tid = threadIdx.x;
    int p0 = blockIdx.x * PTS;
    double regSum = 0.0, regSq = 0.0;
    float sc = 0.f, sh = 0.f;
    if (PASS == 1 && tid < O) { sc = ss[tid]; sh = ss[O + tid]; }
    for (int pi = 0; pi < PTS; ++pi) {
        int p = p0 + pi;
        int b = p >> 11;
        const float* xb = x + (size_t)b * NPT * ld;
        const float* xr = x + (size_t)p * ld;
        if (tid < KNN) sidx[tid] = idx[p * KNN + tid];
        for (int c = tid; c < C; c += 256) sctr[c] = xr[c];
        __syncthreads();
        for (int j = tid; j < KNN * C; j += 256) {
            int kk = j / C, c = j - kk * C;
            snb[j] = xb[(size_t)sidx[kk] * ld + c];
        }
        __syncthreads();
        if (tid < O) {
            const float* Wo = W + tid * 2 * C;
            float s = 0.f;
            float acc[KNN];
#pragma unroll
            for (int kk = 0; kk < KNN; ++kk) acc[kk] = 0.f;
            for (int c = 0; c < C; ++c) {
                float w1 = Wo[c];
                float w2 = Wo[C + c];
                s += (w2 - w1) * sctr[c];
#pragma unroll
                for (int kk = 0; kk < KNN; ++kk) acc[kk] += w1 * snb[kk * C + c];
            }
            if (PASS == 0) {
#pragma unroll
                for (int kk = 0; kk < KNN; ++kk) {
                    double h = (double)(acc[kk] + s);
                    regSum += h; regSq += h * h;
                }
            } else {
                float m = -FLT_MAX;
#pragma unroll
                for (int kk = 0; kk < KNN; ++kk) {
                    float h = (acc[kk] + s) * sc + sh;
                    h = h > 0.f ? h : 0.2f * h;
                    m = fmaxf(m, h);
                }
                out[(size_t)p * ldo + tid] = m;
            }
        }
        __syncthreads();
    }
    if (PASS == 0 && tid < O) {
        partials[(size_t)blockIdx.x * 2 * O + tid]     = regSum;
        partials[(size_t)blockIdx.x * 2 * O + O + tid] = regSq;
    }
}

// ---------------- BN finalize: deterministic fixed-order reduction ----------------
__global__ __launch_bounds__(256) void k_bnstats(const double* __restrict__ partials,
                                                 const float* __restrict__ g,
                                                 const float* __restrict__ be,
                                                 float* __restrict__ ss, int O) {
    int o = threadIdx.x;
    if (o >= O) return;
    double sum = 0.0, sq = 0.0;
    for (int b = 0; b < STAT_BLOCKS; ++b) {
        sum += partials[(size_t)b * 2 * O + o];
        sq  += partials[(size_t)b * 2 * O + O + o];
    }
    const double M = 163840.0;   // 8*2048*10
    double mu = sum / M;
    double var = sq / M - mu * mu;
    if (var < 0.0) var = 0.0;
    float scv = (float)((double)g[o] / sqrt(var + 1e-5));
    ss[o] = scv;
    ss[O + o] = be[o] - (float)mu * scv;
}

// ---------------- dense: out[p][o] = act(in[p]·W[o] + bias) ----------------
template<int ACT>
__global__ __launch_bounds__(256) void k_dense(const float* __restrict__ in, int ldi, int Cin,
                                               const float* __restrict__ W,
                                               const float* __restrict__ bias,
                                               float* __restrict__ out, int ldo, int Cout) {
    const int PTSD = 8;
    extern __shared__ float lds[];   // PTSD * Cin
    int p0 = blockIdx.x * PTSD;
    for (int pi = 0; pi < PTSD; ++pi) {
        const float* row = in + (size_t)(p0 + pi) * ldi;
        for (int c = threadIdx.x; c < Cin; c += 256) lds[pi * Cin + c] = row[c];
    }
    __syncthreads();
    for (int o = threadIdx.x; o < Cout; o += 256) {
        float acc[PTSD];
#pragma unroll
        for (int pi = 0; pi < PTSD; ++pi) acc[pi] = 0.f;
        const float* Wo = W + (size_t)o * Cin;
#pragma unroll 4
        for (int c = 0; c < Cin; ++c) {
            float w = Wo[c];
#pragma unroll
            for (int pi = 0; pi < PTSD; ++pi) acc[pi] += w * lds[pi * Cin + c];
        }
        float bv = bias ? bias[o] : 0.f;
#pragma unroll
        for (int pi = 0; pi < PTSD; ++pi) {
            float v = acc[pi] + bv;
            if (ACT) v = v > 0.f ? v : 0.2f * v;
            out[(size_t)(p0 + pi) * ldo + o] = v;
        }
    }
}

extern "C" void kernel_launch(void* const* d_in, const int* in_sizes, int n_in,
                              void* d_out, int out_size, void* d_ws, size_t ws_size,
                              hipStream_t stream) {
    const float* x   = (const float*)d_in[0];
    const float* W1  = (const float*)d_in[1];
    const float* g1  = (const float*)d_in[2];
    const float* b1  = (const float*)d_in[3];
    const float* W2  = (const float*)d_in[4];
    const float* g2  = (const float*)d_in[5];
    const float* b2  = (const float*)d_in[6];
    const float* W3  = (const float*)d_in[7];
    const float* g3  = (const float*)d_in[8];
    const float* b3  = (const float*)d_in[9];
    const float* W4  = (const float*)d_in[10];
    const float* g4  = (const float*)d_in[11];
    const float* b4  = (const float*)d_in[12];
    const float* W5  = (const float*)d_in[13];
    const float* W6  = (const float*)d_in[14];
    const float* Wd1 = (const float*)d_in[15];
    const float* bd1 = (const float*)d_in[16];
    const float* Wd2 = (const float*)d_in[17];
    const float* bd2 = (const float*)d_in[18];

    char* ws = (char*)d_ws;
    float* cat    = (float*)(ws);                 // 16384*512 f32 = 33,554,432 B
    float* h5     = (float*)(ws + 33554432);      // 16384*256 f32 (tail only)
    double* norms = (double*)(ws + 33554432);     // overlay on h5: 16384 f64 (knn phase)
    double* parts = (double*)(ws + 33685504);     // overlay on h5+128K: 1024*512 f64 = 4 MB (stats phase)
    float* pts    = (float*)(ws + 50331648);      // 16384*24  f32
    int*   idx    = (int*)  (ws + 51904512);      // 16384*10  i32
    float* ssb    = (float*)(ws + 52563968);      // 1024 f32
    float* tmp    = (float*)(ws);                 // overlay (dead cat): 16384*552 f32

    float* feat = (float*)d_out;                // 16384 x 552
    float* logi = (float*)d_out + 9043968;      // 16384 x 255

    dim3 blk(256);

    k_pts<<<dim3((NPTS_TOTAL * 24 + 255) / 256), blk, 0, stream>>>(x, pts);

    // ---- layer 1: C=24, O=64 ----
    k_norm<<<dim3(64), blk, 0, stream>>>(pts, 24, 24, norms);
    k_knn<6><<<dim3(NPTS_TOTAL), blk, 0, stream>>>(pts, 24, norms, idx);
    k_conv<0, 24, 64><<<dim3(STAT_BLOCKS), blk, 0, stream>>>(pts, 24, idx, W1, parts, nullptr, nullptr, 0);
    k_bnstats<<<dim3(1), blk, 0, stream>>>(parts, g1, b1, ssb, 64);
    k_conv<1, 24, 64><<<dim3(STAT_BLOCKS), blk, 0, stream>>>(pts, 24, idx, W1, nullptr, ssb, cat + 0, 512);

    // ---- layer 2: C=64, O=64 ----
    k_norm<<<dim3(64), blk, 0, stream>>>(cat + 0, 512, 64, norms);
    k_knn<16><<<dim3(NPTS_TOTAL), blk, 0, stream>>>(cat + 0, 512, norms, idx);
    k_conv<0, 64, 64><<<dim3(STAT_BLOCKS), blk, 0, stream>>>(cat + 0, 512, idx, W2, parts, nullptr, nullptr, 0);
    k_bnstats<<<dim3(1), blk, 0, stream>>>(parts, g2, b2, ssb, 64);
    k_conv<1, 64, 64><<<dim3(STAT_BLOCKS), blk, 0, stream>>>(cat + 0, 512, idx, W2, nullptr, ssb, cat + 64, 512);

    // ---- layer 3: C=64, O=128 ----
    k_norm<<<dim3(64), blk, 0, stream>>>(cat + 64, 512, 64, norms);
    k_knn<16><<<dim3(NPTS_TOTAL), blk, 0, stream>>>(cat + 64, 512, norms, idx);
    k_conv<0, 64, 128><<<dim3(STAT_BLOCKS), blk, 0, stream>>>(cat + 64, 512, idx, W3, parts, nullptr, nullptr, 0);
    k_bnstats<<<dim3(1), blk, 0, stream>>>(parts, g3, b3, ssb, 128);
    k_conv<1, 64, 128><<<dim3(STAT_BLOCKS), blk, 0, stream>>>(cat + 64, 512, idx, W3, nullptr, ssb, cat + 128, 512);

    // ---- layer 4: C=128, O=256 ----
    k_norm<<<dim3(64), blk, 0, stream>>>(cat + 128, 512, 128, norms);
    k_knn<32><<<dim3(NPTS_TOTAL), blk, 0, stream>>>(cat + 128, 512, norms, idx);
    k_conv<0, 128, 256><<<dim3(STAT_BLOCKS), blk, 0, stream>>>(cat + 128, 512, idx, W4, parts, nullptr, nullptr, 0);
    k_bnstats<<<dim3(1), blk, 0, stream>>>(parts, g4, b4, ssb, 256);
    k_conv<1, 128, 256><<<dim3(STAT_BLOCKS), blk, 0, stream>>>(cat + 128, 512, idx, W4, nullptr, ssb, cat + 256, 512);

    // ---- tail ----
    k_dense<1><<<dim3(NPTS_TOTAL / 8), blk, 8 * 512 * 4, stream>>>(cat, 512, 512, W5, nullptr, h5, 256, 256);
    k_dense<1><<<dim3(NPTS_TOTAL / 8), blk, 8 * 256 * 4, stream>>>(h5, 256, 256, W6, nullptr, feat, 552, 552);
    k_dense<0><<<dim3(NPTS_TOTAL / 8), blk, 8 * 552 * 4, stream>>>(feat, 552, 552, Wd1, bd1, tmp, 552, 552);
    k_dense<0><<<dim3(NPTS_TOTAL / 8), blk, 8 * 552 * 4, stream>>>(tmp, 552, 552, Wd2, bd2, logi, 255, 255);
}

// Round 4
// 7535.848 us; speedup vs baseline: 1.2467x; 1.2467x over previous
//
#include <hip/hip_runtime.h>
#include <float.h>
#include <math.h>

#define NPT 2048        // points per batch
#define NBATCH 8
#define NPTS_TOTAL 16384
#define KNN 10
#define STAT_BLOCKS 1024
#define NCHUNK 4
#define CHUNKSZ 512     // 2048 / NCHUNK
#define TR 16           // candidate tile rows
#define CB 8            // channel block

// ---------------- transpose (S,B,K,D) -> pts[b*2048+n][24] ----------------
__global__ __launch_bounds__(256) void k_pts(const float* __restrict__ x, float* __restrict__ pts) {
    int i = blockIdx.x * 256 + threadIdx.x;
    if (i >= NPTS_TOTAL * 24) return;
    int p = i / 24, c = i - p * 24;
    int b = p >> 11, n = p & 2047;
    pts[i] = x[(n * 8 + b) * 24 + c];
}

// ---------------- prep: f64 norms + transposed f32 copy qT[c][p] ----------------
__global__ __launch_bounds__(256) void k_prep(const float* __restrict__ x, int ld, int C,
                                              double* __restrict__ norms, float* __restrict__ qT) {
    int p = blockIdx.x * 256 + threadIdx.x;
    if (p >= NPTS_TOTAL) return;
    const float* row = x + (size_t)p * ld;
    double s = 0.0;
    for (int c = 0; c < C; ++c) {
        float v = row[c];
        qT[(size_t)c * NPTS_TOTAL + p] = v;
        double dv = (double)v;
        s += dv * dv;
    }
    norms[p] = s;
}

// ---------------- KNN: query-per-thread, chunked candidates, reg top-10 ----------------
// grid = (NCHUNK, 64); block = 256. Thread owns query p = blockIdx.y*256+tid.
// Candidates staged in LDS f32 tiles (broadcast reads); dot accumulated in f64.
// Per-chunk sorted top-10 written to pk/pi; merged exactly by k_kmerge.
template<int C>
__global__ __launch_bounds__(256) void k_knn2(const float* __restrict__ x, int ld,
                                              const double* __restrict__ norms,
                                              const float* __restrict__ qT,
                                              double* __restrict__ pk, int* __restrict__ pi) {
    __shared__ float tile[TR * C];
    __shared__ double tnorm[TR];
    const int tid = threadIdx.x;
    const int chunk = blockIdx.x;
    const int p = blockIdx.y * 256 + tid;
    const int b = p >> 11;
    const float* xb = x + (size_t)b * NPT * ld;
    const double* nbase = norms + (size_t)b * NPT;
    const double nn = norms[p];
    const int cand0 = chunk * CHUNKSZ;           // within-batch candidate base

    double keys[10]; int ids[10];
#pragma unroll
    for (int t = 0; t < 10; ++t) { keys[t] = -DBL_MAX; ids[t] = 0; }

    for (int t0 = 0; t0 < CHUNKSZ; t0 += TR) {
        __syncthreads();   // protect previous tile reads
        for (int i = tid; i < TR * C / 4; i += 256) {
            int r = i / (C / 4), c4 = i - r * (C / 4);
            ((float4*)tile)[i] = ((const float4*)(xb + (size_t)(cand0 + t0 + r) * ld))[c4];
        }
        if (tid < TR) tnorm[tid] = nbase[cand0 + t0 + tid];
        __syncthreads();

        double acc[TR];
#pragma unroll
        for (int j = 0; j < TR; ++j) acc[j] = 0.0;

        for (int cb = 0; cb < C / CB; ++cb) {
            double qd[CB];
#pragma unroll
            for (int e = 0; e < CB; ++e)
                qd[e] = (double)qT[(size_t)(cb * CB + e) * NPTS_TOTAL + p];
#pragma unroll
            for (int j = 0; j < TR; ++j) {
                double a = acc[j];
#pragma unroll
                for (int e = 0; e < CB; ++e)
                    a = fma(qd[e], (double)tile[j * C + cb * CB + e], a);
                acc[j] = a;
            }
        }
#pragma unroll
        for (int j = 0; j < TR; ++j) {
            double d = 2.0 * acc[j] - nn - tnorm[j];
            int m = cand0 + t0 + j;
            if (d > keys[9]) {          // strict >: ascending m => lower-index tie-break
                double cv = d; int ci = m;
#pragma unroll
                for (int t = 0; t < 10; ++t) {
                    bool sw = cv > keys[t];
                    double tk = keys[t]; int ti = ids[t];
                    if (sw) { keys[t] = cv; ids[t] = ci; cv = tk; ci = ti; }
                }
            }
        }
    }
#pragma unroll
    for (int t = 0; t < 10; ++t) {
        pk[((size_t)p * NCHUNK + chunk) * 10 + t] = keys[t];
        pi[((size_t)p * NCHUNK + chunk) * 10 + t] = ids[t];
    }
}

// ---------------- merge NCHUNK sorted 10-lists -> final top-10 ----------------
__global__ __launch_bounds__(256) void k_kmerge(const double* __restrict__ pk,
                                                const int* __restrict__ pi,
                                                int* __restrict__ idx_out) {
    int p = blockIdx.x * 256 + threadIdx.x;
    if (p >= NPTS_TOTAL) return;
    int h0 = 0, h1 = 0, h2 = 0, h3 = 0;
    const double* base = pk + (size_t)p * NCHUNK * 10;
    const int* ibase = pi + (size_t)p * NCHUNK * 10;
    for (int t = 0; t < 10; ++t) {
        double v0 = (h0 < 10) ? base[0 * 10 + h0] : -DBL_MAX;
        double v1 = (h1 < 10) ? base[1 * 10 + h1] : -DBL_MAX;
        double v2 = (h2 < 10) ? base[2 * 10 + h2] : -DBL_MAX;
        double v3 = (h3 < 10) ? base[3 * 10 + h3] : -DBL_MAX;
        double bv = v0; int bc = 0;
        if (v1 > bv) { bv = v1; bc = 1; }   // strict >: ties keep lower chunk (lower idx)
        if (v2 > bv) { bv = v2; bc = 2; }
        if (v3 > bv) { bv = v3; bc = 3; }
        int hh = (bc == 0) ? h0 : (bc == 1) ? h1 : (bc == 2) ? h2 : h3;
        idx_out[p * 10 + t] = ibase[bc * 10 + hh];
        if (bc == 0) h0++; else if (bc == 1) h1++; else if (bc == 2) h2++; else h3++;
    }
}

// ---------------- edgeconv (two-pass) ----------------
// h[k][o] = W[o][0:C]·nb_k + (W[o][C:2C]-W[o][0:C])·ctr
// PASS 0: per-block partial sum/sumsq of h per channel (f64, deterministic).
// PASS 1: out = max_k leaky(h*sc+sh)
template<int PASS, int C, int O>
__global__ __launch_bounds__(256) void k_conv(const float* __restrict__ x, int ld,
                                              const int* __restrict__ idx,
                                              const float* __restrict__ W,
                                              double* __restrict__ partials,
                                              const float* __restrict__ ss,
                                              float* __restrict__ out, int ldo) {
    const int PTS = 16;
    __shared__ float sctr[C];
    __shared__ float snb[KNN * C];
    __shared__ int sidx[KNN];
    int tid = threadIdx.x;
    int p0 = blockIdx.x * PTS;
    double regSum = 0.0, regSq = 0.0;
    float sc = 0.f, sh = 0.f;
    if (PASS == 1 && tid < O) { sc = ss[tid]; sh = ss[O + tid]; }
    for (int pi = 0; pi < PTS; ++pi) {
        int p = p0 + pi;
        int b = p >> 11;
        const float* xb = x + (size_t)b * NPT * ld;
        const float* xr = x + (size_t)p * ld;
        if (tid < KNN) sidx[tid] = idx[p * KNN + tid];
        for (int c = tid; c < C; c += 256) sctr[c] = xr[c];
        __syncthreads();
        for (int j = tid; j < KNN * C; j += 256) {
            int kk = j / C, c = j - kk * C;
            snb[j] = xb[(size_t)sidx[kk] * ld + c];
        }
        __syncthreads();
        if (tid < O) {
            const float* Wo = W + tid * 2 * C;
            float s = 0.f;
            float acc[KNN];
#pragma unroll
            for (int kk = 0; kk < KNN; ++kk) acc[kk] = 0.f;
            for (int c = 0; c < C; ++c) {
                float w1 = Wo[c];
                float w2 = Wo[C + c];
                s += (w2 - w1) * sctr[c];
#pragma unroll
                for (int kk = 0; kk < KNN; ++kk) acc[kk] += w1 * snb[kk * C + c];
            }
            if (PASS == 0) {
#pragma unroll
                for (int kk = 0; kk < KNN; ++kk) {
                    double h = (double)(acc[kk] + s);
                    regSum += h; regSq += h * h;
                }
            } else {
                float m = -FLT_MAX;
#pragma unroll
                for (int kk = 0; kk < KNN; ++kk) {
                    float h = (acc[kk] + s) * sc + sh;
                    h = h > 0.f ? h : 0.2f * h;
                    m = fmaxf(m, h);
                }
                out[(size_t)p * ldo + tid] = m;
            }
        }
        __syncthreads();
    }
    if (PASS == 0 && tid < O) {
        partials[(size_t)blockIdx.x * 2 * O + tid]     = regSum;
        partials[(size_t)blockIdx.x * 2 * O + O + tid] = regSq;
    }
}

// ---------------- BN finalize: deterministic fixed-order reduction ----------------
__global__ __launch_bounds__(256) void k_bnstats(const double* __restrict__ partials,
                                                 const float* __restrict__ g,
                                                 const float* __restrict__ be,
                                                 float* __restrict__ ss, int O) {
    int o = threadIdx.x;
    if (o >= O) return;
    double sum = 0.0, sq = 0.0;
    for (int b = 0; b < STAT_BLOCKS; ++b) {
        sum += partials[(size_t)b * 2 * O + o];
        sq  += partials[(size_t)b * 2 * O + O + o];
    }
    const double M = 163840.0;   // 8*2048*10
    double mu = sum / M;
    double var = sq / M - mu * mu;
    if (var < 0.0) var = 0.0;
    float scv = (float)((double)g[o] / sqrt(var + 1e-5));
    ss[o] = scv;
    ss[O + o] = be[o] - (float)mu * scv;
}

// ---------------- dense: out[p][o] = act(in[p]·W[o] + bias) ----------------
template<int ACT>
__global__ __launch_bounds__(256) void k_dense(const float* __restrict__ in, int ldi, int Cin,
                                               const float* __restrict__ W,
                                               const float* __restrict__ bias,
                                               float* __restrict__ out, int ldo, int Cout) {
    const int PTSD = 8;
    extern __shared__ float lds[];   // PTSD * Cin
    int p0 = blockIdx.x * PTSD;
    for (int pi = 0; pi < PTSD; ++pi) {
        const float* row = in + (size_t)(p0 + pi) * ldi;
        for (int c = threadIdx.x; c < Cin; c += 256) lds[pi * Cin + c] = row[c];
    }
    __syncthreads();
    for (int o = threadIdx.x; o < Cout; o += 256) {
        float acc[PTSD];
#pragma unroll
        for (int pi = 0; pi < PTSD; ++pi) acc[pi] = 0.f;
        const float* Wo = W + (size_t)o * Cin;
#pragma unroll 4
        for (int c = 0; c < Cin; ++c) {
            float w = Wo[c];
#pragma unroll
            for (int pi = 0; pi < PTSD; ++pi) acc[pi] += w * lds[pi * Cin + c];
        }
        float bv = bias ? bias[o] : 0.f;
#pragma unroll
        for (int pi = 0; pi < PTSD; ++pi) {
            float v = acc[pi] + bv;
            if (ACT) v = v > 0.f ? v : 0.2f * v;
            out[(size_t)(p0 + pi) * ldo + o] = v;
        }
    }
}

extern "C" void kernel_launch(void* const* d_in, const int* in_sizes, int n_in,
                              void* d_out, int out_size, void* d_ws, size_t ws_size,
                              hipStream_t stream) {
    const float* x   = (const float*)d_in[0];
    const float* W1  = (const float*)d_in[1];
    const float* g1  = (const float*)d_in[2];
    const float* b1  = (const float*)d_in[3];
    const float* W2  = (const float*)d_in[4];
    const float* g2  = (const float*)d_in[5];
    const float* b2  = (const float*)d_in[6];
    const float* W3  = (const float*)d_in[7];
    const float* g3  = (const float*)d_in[8];
    const float* b3  = (const float*)d_in[9];
    const float* W4  = (const float*)d_in[10];
    const float* g4  = (const float*)d_in[11];
    const float* b4  = (const float*)d_in[12];
    const float* W5  = (const float*)d_in[13];
    const float* W6  = (const float*)d_in[14];
    const float* Wd1 = (const float*)d_in[15];
    const float* bd1 = (const float*)d_in[16];
    const float* Wd2 = (const float*)d_in[17];
    const float* bd2 = (const float*)d_in[18];

    char* ws = (char*)d_ws;
    float* cat    = (float*)(ws);                 // [0, 33554432)
    double* norms = (double*)(ws + 33554432);     // 131072 B
    float* qT     = (float*)(ws + 33685504);      // 8388608 B (C<=128 transposed f32)
    double* pk    = (double*)(ws + 42074112);     // 5242880 B (16384*4*10 f64)
    int*   pi     = (int*)  (ws + 47316992);      // 2621440 B
    float* pts    = (float*)(ws + 50331648);      // 1572864 B
    int*   idx    = (int*)  (ws + 51904512);      // 655360 B
    float* ssb    = (float*)(ws + 52563968);      // 1024 f32
    double* parts = (double*)(ws + 33685504);     // 4 MB, overlays qT (disjoint lifetime)
    float* h5     = (float*)(ws + 33554432);      // tail only, overlays norms/qT
    float* tmp    = (float*)(ws);                 // tail only, overlays dead cat

    float* feat = (float*)d_out;                // 16384 x 552
    float* logi = (float*)d_out + 9043968;      // 16384 x 255

    dim3 blk(256);
    dim3 kgrid(NCHUNK, 64);

    k_pts<<<dim3((NPTS_TOTAL * 24 + 255) / 256), blk, 0, stream>>>(x, pts);

    // ---- layer 1: C=24, O=64 ----
    k_prep<<<dim3(64), blk, 0, stream>>>(pts, 24, 24, norms, qT);
    k_knn2<24><<<kgrid, blk, 0, stream>>>(pts, 24, norms, qT, pk, pi);
    k_kmerge<<<dim3(64), blk, 0, stream>>>(pk, pi, idx);
    k_conv<0, 24, 64><<<dim3(STAT_BLOCKS), blk, 0, stream>>>(pts, 24, idx, W1, parts, nullptr, nullptr, 0);
    k_bnstats<<<dim3(1), blk, 0, stream>>>(parts, g1, b1, ssb, 64);
    k_conv<1, 24, 64><<<dim3(STAT_BLOCKS), blk, 0, stream>>>(pts, 24, idx, W1, nullptr, ssb, cat + 0, 512);

    // ---- layer 2: C=64, O=64 ----
    k_prep<<<dim3(64), blk, 0, stream>>>(cat + 0, 512, 64, norms, qT);
    k_knn2<64><<<kgrid, blk, 0, stream>>>(cat + 0, 512, norms, qT, pk, pi);
    k_kmerge<<<dim3(64), blk, 0, stream>>>(pk, pi, idx);
    k_conv<0, 64, 64><<<dim3(STAT_BLOCKS), blk, 0, stream>>>(cat + 0, 512, idx, W2, parts, nullptr, nullptr, 0);
    k_bnstats<<<dim3(1), blk, 0, stream>>>(parts, g2, b2, ssb, 64);
    k_conv<1, 64, 64><<<dim3(STAT_BLOCKS), blk, 0, stream>>>(cat + 0, 512, idx, W2, nullptr, ssb, cat + 64, 512);

    // ---- layer 3: C=64, O=128 ----
    k_prep<<<dim3(64), blk, 0, stream>>>(cat + 64, 512, 64, norms, qT);
    k_knn2<64><<<kgrid, blk, 0, stream>>>(cat + 64, 512, norms, qT, pk, pi);
    k_kmerge<<<dim3(64), blk, 0, stream>>>(pk, pi, idx);
    k_conv<0, 64, 128><<<dim3(STAT_BLOCKS), blk, 0, stream>>>(cat + 64, 512, idx, W3, parts, nullptr, nullptr, 0);
    k_bnstats<<<dim3(1), blk, 0, stream>>>(parts, g3, b3, ssb, 128);
    k_conv<1, 64, 128><<<dim3(STAT_BLOCKS), blk, 0, stream>>>(cat + 64, 512, idx, W3, nullptr, ssb, cat + 128, 512);

    // ---- layer 4: C=128, O=256 ----
    k_prep<<<dim3(64), blk, 0, stream>>>(cat + 128, 512, 128, norms, qT);
    k_knn2<128><<<kgrid, blk, 0, stream>>>(cat + 128, 512, norms, qT, pk, pi);
    k_kmerge<<<dim3(64), blk, 0, stream>>>(pk, pi, idx);
    k_conv<0, 128, 256><<<dim3(STAT_BLOCKS), blk, 0, stream>>>(cat + 128, 512, idx, W4, parts, nullptr, nullptr, 0);
    k_bnstats<<<dim3(1), blk, 0, stream>>>(parts, g4, b4, ssb, 256);
    k_conv<1, 128, 256><<<dim3(STAT_BLOCKS), blk, 0, stream>>>(cat + 128, 512, idx, W4, nullptr, ssb, cat + 256, 512);

    // ---- tail ----
    k_dense<1><<<dim3(NPTS_TOTAL / 8), blk, 8 * 512 * 4, stream>>>(cat, 512, 512, W5, nullptr, h5, 256, 256);
    k_dense<1><<<dim3(NPTS_TOTAL / 8), blk, 8 * 256 * 4, stream>>>(h5, 256, 256, W6, nullptr, feat, 552, 552);
    k_dense<0><<<dim3(NPTS_TOTAL / 8), blk, 8 * 552 * 4, stream>>>(feat, 552, 552, Wd1, bd1, tmp, 552, 552);
    k_dense<0><<<dim3(NPTS_TOTAL / 8), blk, 8 * 552 * 4, stream>>>(tmp, 552, 552, Wd2, bd2, logi, 255, 255);
}

// Round 5
// 5626.377 us; speedup vs baseline: 1.6699x; 1.3394x over previous
//
#include <hip/hip_runtime.h>
#include <float.h>
#include <math.h>

#define NPT 2048        // points per batch
#define NBATCH 8
#define NPTS_TOTAL 16384
#define KNN 10
#define STAT_BLOCKS 1024
#define NCHUNK 8
#define CHUNKSZ 256     // 2048 / NCHUNK
#define TR 32           // candidate tile rows
#define CB 8            // channel block

// ---------------- transpose (S,B,K,D) -> pts[b*2048+n][24] ----------------
__global__ __launch_bounds__(256) void k_pts(const float* __restrict__ x, float* __restrict__ pts) {
    int i = blockIdx.x * 256 + threadIdx.x;
    if (i >= NPTS_TOTAL * 24) return;
    int p = i / 24, c = i - p * 24;
    int b = p >> 11, n = p & 2047;
    pts[i] = x[(n * 8 + b) * 24 + c];
}

// ---------------- prep: f64 norms + transposed f32 copy qT[c][p] ----------------
__global__ __launch_bounds__(256) void k_prep(const float* __restrict__ x, int ld, int C,
                                              double* __restrict__ norms, float* __restrict__ qT) {
    int p = blockIdx.x * 256 + threadIdx.x;
    if (p >= NPTS_TOTAL) return;
    const float* row = x + (size_t)p * ld;
    double s = 0.0;
    for (int c = 0; c < C; ++c) {
        float v = row[c];
        qT[(size_t)c * NPTS_TOTAL + p] = v;
        double dv = (double)v;
        s += dv * dv;
    }
    norms[p] = s;
}

// ---------------- KNN: query-per-thread, chunked candidates, reg top-10 ----------------
// grid = (NCHUNK, 64); block = 256. Thread owns query p = blockIdx.y*256+tid.
// Candidates staged in LDS f32 tiles (uniform broadcast b128 reads); f64 dot.
template<int C>
__global__ __launch_bounds__(256, 2) void k_knn2(const float* __restrict__ x, int ld,
                                                 const double* __restrict__ norms,
                                                 const float* __restrict__ qT,
                                                 double* __restrict__ pk, int* __restrict__ pi) {
    __shared__ float tile[TR * C];
    __shared__ double tnorm[TR];
    const int tid = threadIdx.x;
    const int chunk = blockIdx.x;
    const int p = blockIdx.y * 256 + tid;
    const int b = p >> 11;
    const float* xb = x + (size_t)b * NPT * ld;
    const double* nbase = norms + (size_t)b * NPT;
    const double nn = norms[p];
    const int cand0 = chunk * CHUNKSZ;           // within-batch candidate base

    double keys[10]; int ids[10];
#pragma unroll
    for (int t = 0; t < 10; ++t) { keys[t] = -DBL_MAX; ids[t] = 0; }

    for (int t0 = 0; t0 < CHUNKSZ; t0 += TR) {
        __syncthreads();   // protect previous tile reads
        for (int i = tid; i < TR * C / 4; i += 256) {
            int r = i / (C / 4), c4 = i - r * (C / 4);
            ((float4*)tile)[i] = ((const float4*)(xb + (size_t)(cand0 + t0 + r) * ld))[c4];
        }
        if (tid < TR) tnorm[tid] = nbase[cand0 + t0 + tid];
        __syncthreads();

        double acc[TR];
#pragma unroll
        for (int j = 0; j < TR; ++j) acc[j] = 0.0;

        for (int cb = 0; cb < C / CB; ++cb) {
            double qd[CB];
#pragma unroll
            for (int e = 0; e < CB; ++e)
                qd[e] = (double)qT[(size_t)(cb * CB + e) * NPTS_TOTAL + p];
#pragma unroll
            for (int j = 0; j < TR; ++j) {
                const float4 t0v = *(const float4*)&tile[j * C + cb * CB];
                const float4 t1v = *(const float4*)&tile[j * C + cb * CB + 4];
                double a = acc[j];
                a = fma(qd[0], (double)t0v.x, a);
                a = fma(qd[1], (double)t0v.y, a);
                a = fma(qd[2], (double)t0v.z, a);
                a = fma(qd[3], (double)t0v.w, a);
                a = fma(qd[4], (double)t1v.x, a);
                a = fma(qd[5], (double)t1v.y, a);
                a = fma(qd[6], (double)t1v.z, a);
                a = fma(qd[7], (double)t1v.w, a);
                acc[j] = a;
            }
        }
#pragma unroll
        for (int j = 0; j < TR; ++j) {
            double d = 2.0 * acc[j] - nn - tnorm[j];
            int m = cand0 + t0 + j;
            if (d > keys[9]) {          // strict >: ascending m => lower-index tie-break
                double cv = d; int ci = m;
#pragma unroll
                for (int t = 0; t < 10; ++t) {
                    bool sw = cv > keys[t];
                    double tk = keys[t]; int ti = ids[t];
                    if (sw) { keys[t] = cv; ids[t] = ci; cv = tk; ci = ti; }
                }
            }
        }
    }
#pragma unroll
    for (int t = 0; t < 10; ++t) {
        pk[((size_t)p * NCHUNK + chunk) * 10 + t] = keys[t];
        pi[((size_t)p * NCHUNK + chunk) * 10 + t] = ids[t];
    }
}

// ---------------- merge NCHUNK sorted 10-lists -> final top-10 ----------------
__global__ __launch_bounds__(256) void k_kmerge(const double* __restrict__ pk,
                                                const int* __restrict__ pi,
                                                int* __restrict__ idx_out) {
    int p = blockIdx.x * 256 + threadIdx.x;
    if (p >= NPTS_TOTAL) return;
    int h[NCHUNK];
#pragma unroll
    for (int c = 0; c < NCHUNK; ++c) h[c] = 0;
    const double* base = pk + (size_t)p * NCHUNK * 10;
    const int* ibase = pi + (size_t)p * NCHUNK * 10;
    for (int t = 0; t < 10; ++t) {
        double bv = -DBL_MAX; int bc = 0;
#pragma unroll
        for (int c = 0; c < NCHUNK; ++c) {
            double v = (h[c] < 10) ? base[c * 10 + h[c]] : -DBL_MAX;
            if (v > bv) { bv = v; bc = c; }   // strict >: ties keep lower chunk (lower idx)
        }
        int sel = 0;
#pragma unroll
        for (int c = 0; c < NCHUNK; ++c) {
            if (c == bc) sel = ibase[c * 10 + h[c]];
            h[c] += (c == bc) ? 1 : 0;
        }
        idx_out[p * 10 + t] = sel;
    }
}

// ---------------- edgeconv (two-pass) ----------------
// h[k][o] = W[o][0:C]·nb_k + (W[o][C:2C]-W[o][0:C])·ctr
// PASS 0: per-block partial sum/sumsq of h per channel (f64, deterministic).
// PASS 1: out = max_k leaky(h*sc+sh)
template<int PASS, int C, int O>
__global__ __launch_bounds__(256) void k_conv(const float* __restrict__ x, int ld,
                                              const int* __restrict__ idx,
                                              const float* __restrict__ W,
                                              double* __restrict__ partials,
                                              const float* __restrict__ ss,
                                              float* __restrict__ out, int ldo) {
    const int PTS = 16;
    __shared__ float sctr[C];
    __shared__ float snb[KNN * C];
    __shared__ int sidx[KNN];
    int tid = threadIdx.x;
    int p0 = blockIdx.x * PTS;
    double regSum = 0.0, regSq = 0.0;
    float sc = 0.f, sh = 0.f;
    if (PASS == 1 && tid < O) { sc = ss[tid]; sh = ss[O + tid]; }
    for (int pi = 0; pi < PTS; ++pi) {
        int p = p0 + pi;
        int b = p >> 11;
        const float* xb = x + (size_t)b * NPT * ld;
        const float* xr = x + (size_t)p * ld;
        if (tid < KNN) sidx[tid] = idx[p * KNN + tid];
        for (int c = tid; c < C; c += 256) sctr[c] = xr[c];
        __syncthreads();
        for (int j = tid; j < KNN * C; j += 256) {
            int kk = j / C, c = j - kk * C;
            snb[j] = xb[(size_t)sidx[kk] * ld + c];
        }
        __syncthreads();
        if (tid < O) {
            const float* Wo = W + tid * 2 * C;
            float s = 0.f;
            float acc[KNN];
#pragma unroll
            for (int kk = 0; kk < KNN; ++kk) acc[kk] = 0.f;
            for (int c = 0; c < C; ++c) {
                float w1 = Wo[c];
                float w2 = Wo[C + c];
                s += (w2 - w1) * sctr[c];
#pragma unroll
                for (int kk = 0; kk < KNN; ++kk) acc[kk] += w1 * snb[kk * C + c];
            }
            if (PASS == 0) {
#pragma unroll
                for (int kk = 0; kk < KNN; ++kk) {
                    double h = (double)(acc[kk] + s);
                    regSum += h; regSq += h * h;
                }
            } else {
                float m = -FLT_MAX;
#pragma unroll
                for (int kk = 0; kk < KNN; ++kk) {
                    float h = (acc[kk] + s) * sc + sh;
                    h = h > 0.f ? h : 0.2f * h;
                    m = fmaxf(m, h);
                }
                out[(size_t)p * ldo + tid] = m;
            }
        }
        __syncthreads();
    }
    if (PASS == 0 && tid < O) {
        partials[(size_t)blockIdx.x * 2 * O + tid]     = regSum;
        partials[(size_t)blockIdx.x * 2 * O + O + tid] = regSq;
    }
}

// ---------------- BN finalize: deterministic fixed-order reduction ----------------
__global__ __launch_bounds__(256) void k_bnstats(const double* __restrict__ partials,
                                                 const float* __restrict__ g,
                                                 const float* __restrict__ be,
                                                 float* __restrict__ ss, int O) {
    int o = threadIdx.x;
    if (o >= O) return;
    double sum = 0.0, sq = 0.0;
    for (int b = 0; b < STAT_BLOCKS; ++b) {
        sum += partials[(size_t)b * 2 * O + o];
        sq  += partials[(size_t)b * 2 * O + O + o];
    }
    const double M = 163840.0;   // 8*2048*10
    double mu = sum / M;
    double var = sq / M - mu * mu;
    if (var < 0.0) var = 0.0;
    float scv = (float)((double)g[o] / sqrt(var + 1e-5));
    ss[o] = scv;
    ss[O + o] = be[o] - (float)mu * scv;
}

// ---------------- dense: out[p][o] = act(in[p]·W[o] + bias) ----------------
template<int ACT>
__global__ __launch_bounds__(256) void k_dense(const float* __restrict__ in, int ldi, int Cin,
                                               const float* __restrict__ W,
                                               const float* __restrict__ bias,
                                               float* __restrict__ out, int ldo, int Cout) {
    const int PTSD = 8;
    extern __shared__ float lds[];   // PTSD * Cin
    int p0 = blockIdx.x * PTSD;
    for (int pi = 0; pi < PTSD; ++pi) {
        const float* row = in + (size_t)(p0 + pi) * ldi;
        for (int c = threadIdx.x; c < Cin; c += 256) lds[pi * Cin + c] = row[c];
    }
    __syncthreads();
    for (int o = threadIdx.x; o < Cout; o += 256) {
        float acc[PTSD];
#pragma unroll
        for (int pi = 0; pi < PTSD; ++pi) acc[pi] = 0.f;
        const float* Wo = W + (size_t)o * Cin;
#pragma unroll 4
        for (int c = 0; c < Cin; ++c) {
            float w = Wo[c];
#pragma unroll
            for (int pi = 0; pi < PTSD; ++pi) acc[pi] += w * lds[pi * Cin + c];
        }
        float bv = bias ? bias[o] : 0.f;
#pragma unroll
        for (int pi = 0; pi < PTSD; ++pi) {
            float v = acc[pi] + bv;
            if (ACT) v = v > 0.f ? v : 0.2f * v;
            out[(size_t)(p0 + pi) * ldo + o] = v;
        }
    }
}

extern "C" void kernel_launch(void* const* d_in, const int* in_sizes, int n_in,
                              void* d_out, int out_size, void* d_ws, size_t ws_size,
                              hipStream_t stream) {
    const float* x   = (const float*)d_in[0];
    const float* W1  = (const float*)d_in[1];
    const float* g1  = (const float*)d_in[2];
    const float* b1  = (const float*)d_in[3];
    const float* W2  = (const float*)d_in[4];
    const float* g2  = (const float*)d_in[5];
    const float* b2  = (const float*)d_in[6];
    const float* W3  = (const float*)d_in[7];
    const float* g3  = (const float*)d_in[8];
    const float* b3  = (const float*)d_in[9];
    const float* W4  = (const float*)d_in[10];
    const float* g4  = (const float*)d_in[11];
    const float* b4  = (const float*)d_in[12];
    const float* W5  = (const float*)d_in[13];
    const float* W6  = (const float*)d_in[14];
    const float* Wd1 = (const float*)d_in[15];
    const float* bd1 = (const float*)d_in[16];
    const float* Wd2 = (const float*)d_in[17];
    const float* bd2 = (const float*)d_in[18];

    char* ws = (char*)d_ws;
    float* cat    = (float*)(ws);                 // [0, 33,554,432)
    double* norms = (double*)(ws + 33554432);     // 131,072 B
    float* qT     = (float*)(ws + 33685504);      // 8,388,608 B
    double* pk    = (double*)(ws + 42074112);     // 16384*8*10 f64 = 10,485,760 B
    int*   pi     = (int*)  (ws + 52559872);      // 5,242,880 B
    float* pts    = (float*)(ws + 57802752);      // 1,572,864 B
    int*   idx    = (int*)  (ws + 59375616);      // 655,360 B
    float* ssb    = (float*)(ws + 60030976);      // 1024 f32
    double* parts = (double*)(ws + 33685504);     // 4 MB, overlays qT (disjoint lifetime)
    float* h5     = (float*)(ws + 33554432);      // tail only, overlays norms/qT/pk head
    float* tmp    = (float*)(ws);                 // tail only, overlays dead cat

    float* feat = (float*)d_out;                // 16384 x 552
    float* logi = (float*)d_out + 9043968;      // 16384 x 255

    dim3 blk(256);
    dim3 kgrid(NCHUNK, 64);

    k_pts<<<dim3((NPTS_TOTAL * 24 + 255) / 256), blk, 0, stream>>>(x, pts);

    // ---- layer 1: C=24, O=64 ----
    k_prep<<<dim3(64), blk, 0, stream>>>(pts, 24, 24, norms, qT);
    k_knn2<24><<<kgrid, blk, 0, stream>>>(pts, 24, norms, qT, pk, pi);
    k_kmerge<<<dim3(64), blk, 0, stream>>>(pk, pi, idx);
    k_conv<0, 24, 64><<<dim3(STAT_BLOCKS), blk, 0, stream>>>(pts, 24, idx, W1, parts, nullptr, nullptr, 0);
    k_bnstats<<<dim3(1), blk, 0, stream>>>(parts, g1, b1, ssb, 64);
    k_conv<1, 24, 64><<<dim3(STAT_BLOCKS), blk, 0, stream>>>(pts, 24, idx, W1, nullptr, ssb, cat + 0, 512);

    // ---- layer 2: C=64, O=64 ----
    k_prep<<<dim3(64), blk, 0, stream>>>(cat + 0, 512, 64, norms, qT);
    k_knn2<64><<<kgrid, blk, 0, stream>>>(cat + 0, 512, norms, qT, pk, pi);
    k_kmerge<<<dim3(64), blk, 0, stream>>>(pk, pi, idx);
    k_conv<0, 64, 64><<<dim3(STAT_BLOCKS), blk, 0, stream>>>(cat + 0, 512, idx, W2, parts, nullptr, nullptr, 0);
    k_bnstats<<<dim3(1), blk, 0, stream>>>(parts, g2, b2, ssb, 64);
    k_conv<1, 64, 64><<<dim3(STAT_BLOCKS), blk, 0, stream>>>(cat + 0, 512, idx, W2, nullptr, ssb, cat + 64, 512);

    // ---- layer 3: C=64, O=128 ----
    k_prep<<<dim3(64), blk, 0, stream>>>(cat + 64, 512, 64, norms, qT);
    k_knn2<64><<<kgrid, blk, 0, stream>>>(cat + 64, 512, norms, qT, pk, pi);
    k_kmerge<<<dim3(64), blk, 0, stream>>>(pk, pi, idx);
    k_conv<0, 64, 128><<<dim3(STAT_BLOCKS), blk, 0, stream>>>(cat + 64, 512, idx, W3, parts, nullptr, nullptr, 0);
    k_bnstats<<<dim3(1), blk, 0, stream>>>(parts, g3, b3, ssb, 128);
    k_conv<1, 64, 128><<<dim3(STAT_BLOCKS), blk, 0, stream>>>(cat + 64, 512, idx, W3, nullptr, ssb, cat + 128, 512);

    // ---- layer 4: C=128, O=256 ----
    k_prep<<<dim3(64), blk, 0, stream>>>(cat + 128, 512, 128, norms, qT);
    k_knn2<128><<<kgrid, blk, 0, stream>>>(cat + 128, 512, norms, qT, pk, pi);
    k_kmerge<<<dim3(64), blk, 0, stream>>>(pk, pi, idx);
    k_conv<0, 128, 256><<<dim3(STAT_BLOCKS), blk, 0, stream>>>(cat + 128, 512, idx, W4, parts, nullptr, nullptr, 0);
    k_bnstats<<<dim3(1), blk, 0, stream>>>(parts, g4, b4, ssb, 256);
    k_conv<1, 128, 256><<<dim3(STAT_BLOCKS), blk, 0, stream>>>(cat + 128, 512, idx, W4, nullptr, ssb, cat + 256, 512);

    // ---- tail ----
    k_dense<1><<<dim3(NPTS_TOTAL / 8), blk, 8 * 512 * 4, stream>>>(cat, 512, 512, W5, nullptr, h5, 256, 256);
    k_dense<1><<<dim3(NPTS_TOTAL / 8), blk, 8 * 256 * 4, stream>>>(h5, 256, 256, W6, nullptr, feat, 552, 552);
    k_dense<0><<<dim3(NPTS_TOTAL / 8), blk, 8 * 552 * 4, stream>>>(feat, 552, 552, Wd1, bd1, tmp, 552, 552);
    k_dense<0><<<dim3(NPTS_TOTAL / 8), blk, 8 * 552 * 4, stream>>>(tmp, 552, 552, Wd2, bd2, logi, 255, 255);
}

// Round 6
// 4611.523 us; speedup vs baseline: 2.0373x; 1.2201x over previous
//
#include <hip/hip_runtime.h>
#include <float.h>
#include <math.h>

#define NPT 2048        // points per batch
#define NBATCH 8
#define NPTS_TOTAL 16384
#define KNN 10
#define STAT_BLOCKS 2048   // conv2 row-blocks (163840 rows / 80)
#define NCHUNK 8
#define CHUNKSZ 256     // 2048 / NCHUNK
#define TR 32           // knn candidate tile rows
#define CB 8            // knn channel block

// ---------------- transpose (S,B,K,D) -> pts[b*2048+n][24] ----------------
__global__ __launch_bounds__(256) void k_pts(const float* __restrict__ x, float* __restrict__ pts) {
    int i = blockIdx.x * 256 + threadIdx.x;
    if (i >= NPTS_TOTAL * 24) return;
    int p = i / 24, c = i - p * 24;
    int b = p >> 11, n = p & 2047;
    pts[i] = x[(n * 8 + b) * 24 + c];
}

// ---------------- prep: f64 norms + transposed f32 copy qT[c][p] ----------------
__global__ __launch_bounds__(256) void k_prep(const float* __restrict__ x, int ld, int C,
                                              double* __restrict__ norms, float* __restrict__ qT) {
    int p = blockIdx.x * 256 + threadIdx.x;
    if (p >= NPTS_TOTAL) return;
    const float* row = x + (size_t)p * ld;
    double s = 0.0;
    for (int c = 0; c < C; ++c) {
        float v = row[c];
        qT[(size_t)c * NPTS_TOTAL + p] = v;
        double dv = (double)v;
        s += dv * dv;
    }
    norms[p] = s;
}

// ---------------- KNN: query-per-thread, chunked candidates, reg top-10 ----------------
template<int C>
__global__ __launch_bounds__(256, 2) void k_knn2(const float* __restrict__ x, int ld,
                                                 const double* __restrict__ norms,
                                                 const float* __restrict__ qT,
                                                 double* __restrict__ pk, int* __restrict__ pi) {
    __shared__ float tile[TR * C];
    __shared__ double tnorm[TR];
    const int tid = threadIdx.x;
    const int chunk = blockIdx.x;
    const int p = blockIdx.y * 256 + tid;
    const int b = p >> 11;
    const float* xb = x + (size_t)b * NPT * ld;
    const double* nbase = norms + (size_t)b * NPT;
    const double nn = norms[p];
    const int cand0 = chunk * CHUNKSZ;           // within-batch candidate base

    double keys[10]; int ids[10];
#pragma unroll
    for (int t = 0; t < 10; ++t) { keys[t] = -DBL_MAX; ids[t] = 0; }

    for (int t0 = 0; t0 < CHUNKSZ; t0 += TR) {
        __syncthreads();   // protect previous tile reads
        for (int i = tid; i < TR * C / 4; i += 256) {
            int r = i / (C / 4), c4 = i - r * (C / 4);
            ((float4*)tile)[i] = ((const float4*)(xb + (size_t)(cand0 + t0 + r) * ld))[c4];
        }
        if (tid < TR) tnorm[tid] = nbase[cand0 + t0 + tid];
        __syncthreads();

        double acc[TR];
#pragma unroll
        for (int j = 0; j < TR; ++j) acc[j] = 0.0;

        for (int cb = 0; cb < C / CB; ++cb) {
            double qd[CB];
#pragma unroll
            for (int e = 0; e < CB; ++e)
                qd[e] = (double)qT[(size_t)(cb * CB + e) * NPTS_TOTAL + p];
#pragma unroll
            for (int j = 0; j < TR; ++j) {
                const float4 t0v = *(const float4*)&tile[j * C + cb * CB];
                const float4 t1v = *(const float4*)&tile[j * C + cb * CB + 4];
                double a = acc[j];
                a = fma(qd[0], (double)t0v.x, a);
                a = fma(qd[1], (double)t0v.y, a);
                a = fma(qd[2], (double)t0v.z, a);
                a = fma(qd[3], (double)t0v.w, a);
                a = fma(qd[4], (double)t1v.x, a);
                a = fma(qd[5], (double)t1v.y, a);
                a = fma(qd[6], (double)t1v.z, a);
                a = fma(qd[7], (double)t1v.w, a);
                acc[j] = a;
            }
        }
#pragma unroll
        for (int j = 0; j < TR; ++j) {
            double d = 2.0 * acc[j] - nn - tnorm[j];
            int m = cand0 + t0 + j;
            if (d > keys[9]) {          // strict >: ascending m => lower-index tie-break
                double cv = d; int ci = m;
#pragma unroll
                for (int t = 0; t < 10; ++t) {
                    bool sw = cv > keys[t];
                    double tk = keys[t]; int ti = ids[t];
                    if (sw) { keys[t] = cv; ids[t] = ci; cv = tk; ci = ti; }
                }
            }
        }
    }
#pragma unroll
    for (int t = 0; t < 10; ++t) {
        pk[((size_t)p * NCHUNK + chunk) * 10 + t] = keys[t];
        pi[((size_t)p * NCHUNK + chunk) * 10 + t] = ids[t];
    }
}

// ---------------- merge NCHUNK sorted 10-lists -> final top-10 ----------------
__global__ __launch_bounds__(256) void k_kmerge(const double* __restrict__ pk,
                                                const int* __restrict__ pi,
                                                int* __restrict__ idx_out) {
    int p = blockIdx.x * 256 + threadIdx.x;
    if (p >= NPTS_TOTAL) return;
    int h[NCHUNK];
#pragma unroll
    for (int c = 0; c < NCHUNK; ++c) h[c] = 0;
    const double* base = pk + (size_t)p * NCHUNK * 10;
    const int* ibase = pi + (size_t)p * NCHUNK * 10;
    for (int t = 0; t < 10; ++t) {
        double bv = -DBL_MAX; int bc = 0;
#pragma unroll
        for (int c = 0; c < NCHUNK; ++c) {
            double v = (h[c] < 10) ? base[c * 10 + h[c]] : -DBL_MAX;
            if (v > bv) { bv = v; bc = c; }   // strict >: ties keep lower chunk (lower idx)
        }
        int sel = 0;
#pragma unroll
        for (int c = 0; c < NCHUNK; ++c) {
            if (c == bc) sel = ibase[c * 10 + h[c]];
            h[c] += (c == bc) ? 1 : 0;
        }
        idx_out[p * 10 + t] = sel;
    }
}

// ---------------- s-GEMM: s[p][o] = sum_c (W2-W1)[o][c] * x[p][c] ----------------
template<int C, int O>
__global__ __launch_bounds__(256, 2) void k_sgemm(const float* __restrict__ x, int ld,
                                                  const float* __restrict__ W,
                                                  float* __restrict__ s) {
    constexpr int C4 = (C / 4 < 8) ? 8 : C / 4;
    __shared__ __align__(16) float smem[(64 + 64) * C4 * 4];
    float4* As = (float4*)smem;
    float4* Bs = (float4*)(smem + 64 * C4 * 4);
    const int tid = threadIdx.x;
    const int p0 = blockIdx.x * 64;
    const int o0 = blockIdx.y * 64;
    for (int i = tid; i < 64 * C4; i += 256) {
        int r = i / C4, c4 = i - r * C4;
        float4 v = make_float4(0.f, 0.f, 0.f, 0.f);
        if (c4 * 4 < C) v = *(const float4*)(x + (size_t)(p0 + r) * ld + c4 * 4);
        As[r * C4 + (c4 ^ (r & 7))] = v;
    }
    for (int i = tid; i < 64 * C4; i += 256) {
        int oo = i / C4, c4 = i - oo * C4;
        float4 v = make_float4(0.f, 0.f, 0.f, 0.f);
        if (c4 * 4 < C) {
            const float* wr = W + (size_t)(o0 + oo) * 2 * C;
            float4 w1 = *(const float4*)(wr + c4 * 4);
            float4 w2 = *(const float4*)(wr + C + c4 * 4);
            v = make_float4(w2.x - w1.x, w2.y - w1.y, w2.z - w1.z, w2.w - w1.w);
        }
        Bs[oo * C4 + (c4 ^ (oo & 7))] = v;
    }
    __syncthreads();
    const int tx = tid & 15, ty = tid >> 4;
    float acc[4][4];
#pragma unroll
    for (int a = 0; a < 4; ++a)
#pragma unroll
        for (int b = 0; b < 4; ++b) acc[a][b] = 0.f;
    for (int c4 = 0; c4 < C4; ++c4) {
        float4 av[4], bv[4];
#pragma unroll
        for (int rj = 0; rj < 4; ++rj) { int r = ty * 4 + rj; av[rj] = As[r * C4 + (c4 ^ (r & 7))]; }
#pragma unroll
        for (int oj = 0; oj < 4; ++oj) { int oo = tx * 4 + oj; bv[oj] = Bs[oo * C4 + (c4 ^ (oo & 7))]; }
#pragma unroll
        for (int rj = 0; rj < 4; ++rj)
#pragma unroll
            for (int oj = 0; oj < 4; ++oj) {
                acc[rj][oj] = fmaf(av[rj].x, bv[oj].x, acc[rj][oj]);
                acc[rj][oj] = fmaf(av[rj].y, bv[oj].y, acc[rj][oj]);
                acc[rj][oj] = fmaf(av[rj].z, bv[oj].z, acc[rj][oj]);
                acc[rj][oj] = fmaf(av[rj].w, bv[oj].w, acc[rj][oj]);
            }
    }
#pragma unroll
    for (int rj = 0; rj < 4; ++rj) {
        float4 v = make_float4(acc[rj][0], acc[rj][1], acc[rj][2], acc[rj][3]);
        *(float4*)(s + (size_t)(p0 + ty * 4 + rj) * O + o0 + tx * 4) = v;
    }
}

// ---------------- edgeconv GEMM: tile 80 gathered rows x 64 o ----------------
// h[r][o] = W1[o]·nb[r] + s[p(r)][o]
// PASS 0: per-o f64 sum/sumsq -> partials[rb][2O].  PASS 1: BN+leaky+max_k -> out
template<int PASS, int C, int O>
__global__ __launch_bounds__(256, 2) void k_conv2(const float* __restrict__ x, int ld,
                                                  const int* __restrict__ idx,
                                                  const float* __restrict__ W,
                                                  const float* __restrict__ sbuf,
                                                  double* __restrict__ partials,
                                                  const float* __restrict__ ss,
                                                  float* __restrict__ out, int ldo) {
    constexpr int C4 = (C / 4 < 8) ? 8 : C / 4;
    __shared__ __align__(16) float smem[(80 + 64) * C4 * 4];
    __shared__ int sidx[80];
    float4* As = (float4*)smem;
    float4* Bs = (float4*)(smem + 80 * C4 * 4);

    const int tid = threadIdx.x;
    const int rb = blockIdx.x;            // 0..2047
    const int o0 = blockIdx.y * 64;
    const int p0 = rb * 8;                // 8 points per block (same batch: 8 | 2048)
    const int b = p0 >> 11;
    const float* xb = x + (size_t)b * NPT * ld;

    if (tid < 80) sidx[tid] = idx[p0 * KNN + tid];
    __syncthreads();

    for (int i = tid; i < 80 * C4; i += 256) {
        int r = i / C4, c4 = i - r * C4;
        float4 v = make_float4(0.f, 0.f, 0.f, 0.f);
        if (c4 * 4 < C) v = *(const float4*)(xb + (size_t)sidx[r] * ld + c4 * 4);
        As[r * C4 + (c4 ^ (r & 7))] = v;
    }
    for (int i = tid; i < 64 * C4; i += 256) {
        int oo = i / C4, c4 = i - oo * C4;
        float4 v = make_float4(0.f, 0.f, 0.f, 0.f);
        if (c4 * 4 < C) v = *(const float4*)(W + (size_t)(o0 + oo) * 2 * C + c4 * 4);
        Bs[oo * C4 + (c4 ^ (oo & 7))] = v;
    }
    __syncthreads();

    const int tx = tid & 15, ty = tid >> 4;
    const int o_l = tx * 4;
    float acc[5][4];
#pragma unroll
    for (int a = 0; a < 5; ++a)
#pragma unroll
        for (int c = 0; c < 4; ++c) acc[a][c] = 0.f;

    for (int c4 = 0; c4 < C4; ++c4) {
        float4 av[5], bv[4];
#pragma unroll
        for (int rj = 0; rj < 5; ++rj) { int r = ty * 5 + rj; av[rj] = As[r * C4 + (c4 ^ (r & 7))]; }
#pragma unroll
        for (int oj = 0; oj < 4; ++oj) { int oo = o_l + oj; bv[oj] = Bs[oo * C4 + (c4 ^ (oo & 7))]; }
#pragma unroll
        for (int rj = 0; rj < 5; ++rj)
#pragma unroll
            for (int oj = 0; oj < 4; ++oj) {
                acc[rj][oj] = fmaf(av[rj].x, bv[oj].x, acc[rj][oj]);
                acc[rj][oj] = fmaf(av[rj].y, bv[oj].y, acc[rj][oj]);
                acc[rj][oj] = fmaf(av[rj].z, bv[oj].z, acc[rj][oj]);
                acc[rj][oj] = fmaf(av[rj].w, bv[oj].w, acc[rj][oj]);
            }
    }

    // rows ty*5..ty*5+4 all belong to point pt = ty>>1 (k 0-4 for even ty, 5-9 odd)
    const int pt = ty >> 1;
    const float4 s4 = *(const float4*)(sbuf + (size_t)(p0 + pt) * O + o0 + o_l);
    const float* s4f = (const float*)&s4;

    if (PASS == 0) {
        double sum[4] = {0, 0, 0, 0}, sq[4] = {0, 0, 0, 0};
#pragma unroll
        for (int rj = 0; rj < 5; ++rj)
#pragma unroll
            for (int oj = 0; oj < 4; ++oj) {
                float hf = acc[rj][oj] + s4f[oj];
                double hd = (double)hf;
                sum[oj] += hd; sq[oj] += hd * hd;
            }
        __syncthreads();
        double* red = (double*)smem;   // [16][64][2] = 16 KB (smem >= 18 KB for all C)
#pragma unroll
        for (int oj = 0; oj < 4; ++oj) {
            red[(ty * 64 + o_l + oj) * 2 + 0] = sum[oj];
            red[(ty * 64 + o_l + oj) * 2 + 1] = sq[oj];
        }
        __syncthreads();
        if (tid < 128) {
            int o = tid & 63, w = tid >> 6;
            double a = 0.0;
            for (int t2 = 0; t2 < 16; ++t2) a += red[(t2 * 64 + o) * 2 + w];
            partials[(size_t)rb * 2 * O + (size_t)w * O + o0 + o] = a;
        }
    } else {
        float m4[4];
#pragma unroll
        for (int oj = 0; oj < 4; ++oj) {
            float sc = ss[o0 + o_l + oj], sh = ss[O + o0 + o_l + oj];
            float m = -FLT_MAX;
#pragma unroll
            for (int rj = 0; rj < 5; ++rj) {
                float h = (acc[rj][oj] + s4f[oj]) * sc + sh;
                h = h > 0.f ? h : 0.2f * h;
                m = fmaxf(m, h);
            }
            m4[oj] = m;
        }
        __syncthreads();
        float* red = smem;             // [16][64]
#pragma unroll
        for (int oj = 0; oj < 4; ++oj) red[ty * 64 + o_l + oj] = m4[oj];
        __syncthreads();
        if ((ty & 1) == 0) {
            float4 o4;
            float* po = (float*)&o4;
#pragma unroll
            for (int oj = 0; oj < 4; ++oj)
                po[oj] = fmaxf(red[ty * 64 + o_l + oj], red[(ty + 1) * 64 + o_l + oj]);
            *(float4*)(out + (size_t)(p0 + pt) * ldo + o0 + o_l) = o4;
        }
    }
}

// ---------------- BN finalize: deterministic fixed-order reduction ----------------
__global__ __launch_bounds__(256) void k_bnstats(const double* __restrict__ partials,
                                                 const float* __restrict__ g,
                                                 const float* __restrict__ be,
                                                 float* __restrict__ ss, int O) {
    int o = threadIdx.x;
    if (o >= O) return;
    double sum = 0.0, sq = 0.0;
    for (int b = 0; b < STAT_BLOCKS; ++b) {
        sum += partials[(size_t)b * 2 * O + o];
        sq  += partials[(size_t)b * 2 * O + O + o];
    }
    const double M = 163840.0;   // 8*2048*10
    double mu = sum / M;
    double var = sq / M - mu * mu;
    if (var < 0.0) var = 0.0;
    float scv = (float)((double)g[o] / sqrt(var + 1e-5));
    ss[o] = scv;
    ss[O + o] = be[o] - (float)mu * scv;
}

// ---------------- dense: out[p][o] = act(in[p]·W[o] + bias) ----------------
template<int ACT>
__global__ __launch_bounds__(256) void k_dense(const float* __restrict__ in, int ldi, int Cin,
                                               const float* __restrict__ W,
                                               const float* __restrict__ bias,
                                               float* __restrict__ out, int ldo, int Cout) {
    const int PTSD = 8;
    extern __shared__ float lds[];   // PTSD * Cin
    int p0 = blockIdx.x * PTSD;
    for (int pi = 0; pi < PTSD; ++pi) {
        const float* row = in + (size_t)(p0 + pi) * ldi;
        for (int c = threadIdx.x; c < Cin; c += 256) lds[pi * Cin + c] = row[c];
    }
    __syncthreads();
    for (int o = threadIdx.x; o < Cout; o += 256) {
        float acc[PTSD];
#pragma unroll
        for (int pi = 0; pi < PTSD; ++pi) acc[pi] = 0.f;
        const float* Wo = W + (size_t)o * Cin;
#pragma unroll 4
        for (int c = 0; c < Cin; ++c) {
            float w = Wo[c];
#pragma unroll
            for (int pi = 0; pi < PTSD; ++pi) acc[pi] += w * lds[pi * Cin + c];
        }
        float bv = bias ? bias[o] : 0.f;
#pragma unroll
        for (int pi = 0; pi < PTSD; ++pi) {
            float v = acc[pi] + bv;
            if (ACT) v = v > 0.f ? v : 0.2f * v;
            out[(size_t)(p0 + pi) * ldo + o] = v;
        }
    }
}

extern "C" void kernel_launch(void* const* d_in, const int* in_sizes, int n_in,
                              void* d_out, int out_size, void* d_ws, size_t ws_size,
                              hipStream_t stream) {
    const float* x   = (const float*)d_in[0];
    const float* W1  = (const float*)d_in[1];
    const float* g1  = (const float*)d_in[2];
    const float* b1  = (const float*)d_in[3];
    const float* W2  = (const float*)d_in[4];
    const float* g2  = (const float*)d_in[5];
    const float* b2  = (const float*)d_in[6];
    const float* W3  = (const float*)d_in[7];
    const float* g3  = (const float*)d_in[8];
    const float* b3  = (const float*)d_in[9];
    const float* W4  = (const float*)d_in[10];
    const float* g4  = (const float*)d_in[11];
    const float* b4  = (const float*)d_in[12];
    const float* W5  = (const float*)d_in[13];
    const float* W6  = (const float*)d_in[14];
    const float* Wd1 = (const float*)d_in[15];
    const float* bd1 = (const float*)d_in[16];
    const float* Wd2 = (const float*)d_in[17];
    const float* bd2 = (const float*)d_in[18];

    char* ws = (char*)d_ws;
    float* cat    = (float*)(ws);                 // [0, 33,554,432)
    double* norms = (double*)(ws + 33554432);     // 131,072 B
    float* qT     = (float*)(ws + 33685504);      // 8,388,608 B (knn phase)
    double* pk    = (double*)(ws + 42074112);     // 10,485,760 B (knn phase)
    int*   pi     = (int*)  (ws + 52559872);      // 5,242,880 B (knn phase)
    float* pts    = (float*)(ws + 57802752);      // 1,572,864 B (layer-1 input)
    int*   idx    = (int*)  (ws + 59375616);      // 655,360 B
    float* ssb    = (float*)(ws + 60030976);      // 1024 f32
    float* sbuf   = (float*)(ws + 33685504);      // <=16.8 MB, overlays qT+pk (conv phase)
    double* parts = (double*)(ws + 50462720);     // <=8.4 MB, overlays pk tail/pi/pts(L4 only)
    float* h5     = (float*)(ws + 33554432);      // tail only
    float* tmp    = (float*)(ws);                 // tail only, overlays dead cat

    float* feat = (float*)d_out;                // 16384 x 552
    float* logi = (float*)d_out + 9043968;      // 16384 x 255

    dim3 blk(256);
    dim3 kgrid(NCHUNK, 64);

    k_pts<<<dim3((NPTS_TOTAL * 24 + 255) / 256), blk, 0, stream>>>(x, pts);

    // ---- layer 1: C=24, O=64 ----
    k_prep<<<dim3(64), blk, 0, stream>>>(pts, 24, 24, norms, qT);
    k_knn2<24><<<kgrid, blk, 0, stream>>>(pts, 24, norms, qT, pk, pi);
    k_kmerge<<<dim3(64), blk, 0, stream>>>(pk, pi, idx);
    k_sgemm<24, 64><<<dim3(256, 1), blk, 0, stream>>>(pts, 24, W1, sbuf);
    k_conv2<0, 24, 64><<<dim3(STAT_BLOCKS, 1), blk, 0, stream>>>(pts, 24, idx, W1, sbuf, parts, nullptr, nullptr, 0);
    k_bnstats<<<dim3(1), blk, 0, stream>>>(parts, g1, b1, ssb, 64);
    k_conv2<1, 24, 64><<<dim3(STAT_BLOCKS, 1), blk, 0, stream>>>(pts, 24, idx, W1, sbuf, nullptr, ssb, cat + 0, 512);

    // ---- layer 2: C=64, O=64 ----
    k_prep<<<dim3(64), blk, 0, stream>>>(cat + 0, 512, 64, norms, qT);
    k_knn2<64><<<kgrid, blk, 0, stream>>>(cat + 0, 512, norms, qT, pk, pi);
    k_kmerge<<<dim3(64), blk, 0, stream>>>(pk, pi, idx);
    k_sgemm<64, 64><<<dim3(256, 1), blk, 0, stream>>>(cat + 0, 512, W2, sbuf);
    k_conv2<0, 64, 64><<<dim3(STAT_BLOCKS, 1), blk, 0, stream>>>(cat + 0, 512, idx, W2, sbuf, parts, nullptr, nullptr, 0);
    k_bnstats<<<dim3(1), blk, 0, stream>>>(parts, g2, b2, ssb, 64);
    k_conv2<1, 64, 64><<<dim3(STAT_BLOCKS, 1), blk, 0, stream>>>(cat + 0, 512, idx, W2, sbuf, nullptr, ssb, cat + 64, 512);

    // ---- layer 3: C=64, O=128 ----
    k_prep<<<dim3(64), blk, 0, stream>>>(cat + 64, 512, 64, norms, qT);
    k_knn2<64><<<kgrid, blk, 0, stream>>>(cat + 64, 512, norms, qT, pk, pi);
    k_kmerge<<<dim3(64), blk, 0, stream>>>(pk, pi, idx);
    k_sgemm<64, 128><<<dim3(256, 2), blk, 0, stream>>>(cat + 64, 512, W3, sbuf);
    k_conv2<0, 64, 128><<<dim3(STAT_BLOCKS, 2), blk, 0, stream>>>(cat + 64, 512, idx, W3, sbuf, parts, nullptr, nullptr, 0);
    k_bnstats<<<dim3(1), blk, 0, stream>>>(parts, g3, b3, ssb, 128);
    k_conv2<1, 64, 128><<<dim3(STAT_BLOCKS, 2), blk, 0, stream>>>(cat + 64, 512, idx, W3, sbuf, nullptr, ssb, cat + 128, 512);

    // ---- layer 4: C=128, O=256 ----
    k_prep<<<dim3(64), blk, 0, stream>>>(cat + 128, 512, 128, norms, qT);
    k_knn2<128><<<kgrid, blk, 0, stream>>>(cat + 128, 512, norms, qT, pk, pi);
    k_kmerge<<<dim3(64), blk, 0, stream>>>(pk, pi, idx);
    k_sgemm<128, 256><<<dim3(256, 4), blk, 0, stream>>>(cat + 128, 512, W4, sbuf);
    k_conv2<0, 128, 256><<<dim3(STAT_BLOCKS, 4), blk, 0, stream>>>(cat + 128, 512, idx, W4, sbuf, parts, nullptr, nullptr, 0);
    k_bnstats<<<dim3(1), blk, 0, stream>>>(parts, g4, b4, ssb, 256);
    k_conv2<1, 128, 256><<<dim3(STAT_BLOCKS, 4), blk, 0, stream>>>(cat + 128, 512, idx, W4, sbuf, nullptr, ssb, cat + 256, 512);

    // ---- tail ----
    k_dense<1><<<dim3(NPTS_TOTAL / 8), blk, 8 * 512 * 4, stream>>>(cat, 512, 512, W5, nullptr, h5, 256, 256);
    k_dense<1><<<dim3(NPTS_TOTAL / 8), blk, 8 * 256 * 4, stream>>>(h5, 256, 256, W6, nullptr, feat, 552, 552);
    k_dense<0><<<dim3(NPTS_TOTAL / 8), blk, 8 * 552 * 4, stream>>>(feat, 552, 552, Wd1, bd1, tmp, 552, 552);
    k_dense<0><<<dim3(NPTS_TOTAL / 8), blk, 8 * 552 * 4, stream>>>(tmp, 552, 552, Wd2, bd2, logi, 255, 255);
}

// Round 7
// 4141.537 us; speedup vs baseline: 2.2685x; 1.1135x over previous
//
#include <hip/hip_runtime.h>
#include <float.h>
#include <math.h>

#define NPT 2048        // points per batch
#define NBATCH 8
#define NPTS_TOTAL 16384
#define KNN 10
#define STAT_BLOCKS 2048   // conv2 row-blocks (163840 rows / 80)
#define NCHUNK 8
#define CHUNKSZ 256     // 2048 / NCHUNK
#define TR 32           // knn candidate tile rows
#define CB 8            // knn channel block

// ---------------- transpose (S,B,K,D) -> pts[b*2048+n][24] ----------------
__global__ __launch_bounds__(256) void k_pts(const float* __restrict__ x, float* __restrict__ pts) {
    int i = blockIdx.x * 256 + threadIdx.x;
    if (i >= NPTS_TOTAL * 24) return;
    int p = i / 24, c = i - p * 24;
    int b = p >> 11, n = p & 2047;
    pts[i] = x[(n * 8 + b) * 24 + c];
}

// ---------------- prep: f64 norms + transposed f32 copy qT[c][p] ----------------
__global__ __launch_bounds__(256) void k_prep(const float* __restrict__ x, int ld, int C,
                                              double* __restrict__ norms, float* __restrict__ qT) {
    int p = blockIdx.x * 256 + threadIdx.x;
    if (p >= NPTS_TOTAL) return;
    const float* row = x + (size_t)p * ld;
    double s = 0.0;
    for (int c = 0; c < C; ++c) {
        float v = row[c];
        qT[(size_t)c * NPTS_TOTAL + p] = v;
        double dv = (double)v;
        s += dv * dv;
    }
    norms[p] = s;
}

// ---------------- KNN: query-per-thread, chunked candidates, reg top-10 ----------------
template<int C>
__global__ __launch_bounds__(256, 2) void k_knn2(const float* __restrict__ x, int ld,
                                                 const double* __restrict__ norms,
                                                 const float* __restrict__ qT,
                                                 double* __restrict__ pk, int* __restrict__ pi) {
    __shared__ float tile[TR * C];
    __shared__ double tnorm[TR];
    const int tid = threadIdx.x;
    const int chunk = blockIdx.x;
    const int p = blockIdx.y * 256 + tid;
    const int b = p >> 11;
    const float* xb = x + (size_t)b * NPT * ld;
    const double* nbase = norms + (size_t)b * NPT;
    const double nn = norms[p];
    const int cand0 = chunk * CHUNKSZ;           // within-batch candidate base

    double keys[10]; int ids[10];
#pragma unroll
    for (int t = 0; t < 10; ++t) { keys[t] = -DBL_MAX; ids[t] = 0; }

    for (int t0 = 0; t0 < CHUNKSZ; t0 += TR) {
        __syncthreads();   // protect previous tile reads
        for (int i = tid; i < TR * C / 4; i += 256) {
            int r = i / (C / 4), c4 = i - r * (C / 4);
            ((float4*)tile)[i] = ((const float4*)(xb + (size_t)(cand0 + t0 + r) * ld))[c4];
        }
        if (tid < TR) tnorm[tid] = nbase[cand0 + t0 + tid];
        __syncthreads();

        double acc[TR];
#pragma unroll
        for (int j = 0; j < TR; ++j) acc[j] = 0.0;

        for (int cb = 0; cb < C / CB; ++cb) {
            double qd[CB];
#pragma unroll
            for (int e = 0; e < CB; ++e)
                qd[e] = (double)qT[(size_t)(cb * CB + e) * NPTS_TOTAL + p];
#pragma unroll
            for (int j = 0; j < TR; ++j) {
                const float4 t0v = *(const float4*)&tile[j * C + cb * CB];
                const float4 t1v = *(const float4*)&tile[j * C + cb * CB + 4];
                double a = acc[j];
                a = fma(qd[0], (double)t0v.x, a);
                a = fma(qd[1], (double)t0v.y, a);
                a = fma(qd[2], (double)t0v.z, a);
                a = fma(qd[3], (double)t0v.w, a);
                a = fma(qd[4], (double)t1v.x, a);
                a = fma(qd[5], (double)t1v.y, a);
                a = fma(qd[6], (double)t1v.z, a);
                a = fma(qd[7], (double)t1v.w, a);
                acc[j] = a;
            }
        }
#pragma unroll
        for (int j = 0; j < TR; ++j) {
            double d = 2.0 * acc[j] - nn - tnorm[j];
            int m = cand0 + t0 + j;
            if (d > keys[9]) {          // strict >: ascending m => lower-index tie-break
                double cv = d; int ci = m;
#pragma unroll
                for (int t = 0; t < 10; ++t) {
                    bool sw = cv > keys[t];
                    double tk = keys[t]; int ti = ids[t];
                    if (sw) { keys[t] = cv; ids[t] = ci; cv = tk; ci = ti; }
                }
            }
        }
    }
#pragma unroll
    for (int t = 0; t < 10; ++t) {
        pk[((size_t)p * NCHUNK + chunk) * 10 + t] = keys[t];
        pi[((size_t)p * NCHUNK + chunk) * 10 + t] = ids[t];
    }
}

// ---------------- merge NCHUNK sorted 10-lists -> final top-10 ----------------
__global__ __launch_bounds__(256) void k_kmerge(const double* __restrict__ pk,
                                                const int* __restrict__ pi,
                                                int* __restrict__ idx_out) {
    int p = blockIdx.x * 256 + threadIdx.x;
    if (p >= NPTS_TOTAL) return;
    int h[NCHUNK];
#pragma unroll
    for (int c = 0; c < NCHUNK; ++c) h[c] = 0;
    const double* base = pk + (size_t)p * NCHUNK * 10;
    const int* ibase = pi + (size_t)p * NCHUNK * 10;
    for (int t = 0; t < 10; ++t) {
        double bv = -DBL_MAX; int bc = 0;
#pragma unroll
        for (int c = 0; c < NCHUNK; ++c) {
            double v = (h[c] < 10) ? base[c * 10 + h[c]] : -DBL_MAX;
            if (v > bv) { bv = v; bc = c; }   // strict >: ties keep lower chunk (lower idx)
        }
        int sel = 0;
#pragma unroll
        for (int c = 0; c < NCHUNK; ++c) {
            if (c == bc) sel = ibase[c * 10 + h[c]];
            h[c] += (c == bc) ? 1 : 0;
        }
        idx_out[p * 10 + t] = sel;
    }
}

// ---------------- s-GEMM: s[p][o] = sum_c (W2-W1)[o][c] * x[p][c] ----------------
template<int C, int O>
__global__ __launch_bounds__(256, 2) void k_sgemm(const float* __restrict__ x, int ld,
                                                  const float* __restrict__ W,
                                                  float* __restrict__ s) {
    constexpr int C4 = (C / 4 < 8) ? 8 : C / 4;
    __shared__ __align__(16) float smem[(64 + 64) * C4 * 4];
    float4* As = (float4*)smem;
    float4* Bs = (float4*)(smem + 64 * C4 * 4);
    const int tid = threadIdx.x;
    const int p0 = blockIdx.x * 64;
    const int o0 = blockIdx.y * 64;
    for (int i = tid; i < 64 * C4; i += 256) {
        int r = i / C4, c4 = i - r * C4;
        float4 v = make_float4(0.f, 0.f, 0.f, 0.f);
        if (c4 * 4 < C) v = *(const float4*)(x + (size_t)(p0 + r) * ld + c4 * 4);
        As[r * C4 + (c4 ^ (r & 7))] = v;
    }
    for (int i = tid; i < 64 * C4; i += 256) {
        int oo = i / C4, c4 = i - oo * C4;
        float4 v = make_float4(0.f, 0.f, 0.f, 0.f);
        if (c4 * 4 < C) {
            const float* wr = W + (size_t)(o0 + oo) * 2 * C;
            float4 w1 = *(const float4*)(wr + c4 * 4);
            float4 w2 = *(const float4*)(wr + C + c4 * 4);
            v = make_float4(w2.x - w1.x, w2.y - w1.y, w2.z - w1.z, w2.w - w1.w);
        }
        Bs[oo * C4 + (c4 ^ (oo & 7))] = v;
    }
    __syncthreads();
    const int tx = tid & 15, ty = tid >> 4;
    float acc[4][4];
#pragma unroll
    for (int a = 0; a < 4; ++a)
#pragma unroll
        for (int b = 0; b < 4; ++b) acc[a][b] = 0.f;
    for (int c4 = 0; c4 < C4; ++c4) {
        float4 av[4], bv[4];
#pragma unroll
        for (int rj = 0; rj < 4; ++rj) { int r = ty * 4 + rj; av[rj] = As[r * C4 + (c4 ^ (r & 7))]; }
#pragma unroll
        for (int oj = 0; oj < 4; ++oj) { int oo = tx * 4 + oj; bv[oj] = Bs[oo * C4 + (c4 ^ (oo & 7))]; }
#pragma unroll
        for (int rj = 0; rj < 4; ++rj)
#pragma unroll
            for (int oj = 0; oj < 4; ++oj) {
                acc[rj][oj] = fmaf(av[rj].x, bv[oj].x, acc[rj][oj]);
                acc[rj][oj] = fmaf(av[rj].y, bv[oj].y, acc[rj][oj]);
                acc[rj][oj] = fmaf(av[rj].z, bv[oj].z, acc[rj][oj]);
                acc[rj][oj] = fmaf(av[rj].w, bv[oj].w, acc[rj][oj]);
            }
    }
#pragma unroll
    for (int rj = 0; rj < 4; ++rj) {
        float4 v = make_float4(acc[rj][0], acc[rj][1], acc[rj][2], acc[rj][3]);
        *(float4*)(s + (size_t)(p0 + ty * 4 + rj) * O + o0 + tx * 4) = v;
    }
}

// ---------------- edgeconv GEMM: tile 80 gathered rows x 64 o ----------------
// h[r][o] = W1[o]·nb[r] + s[p(r)][o]
// PASS 0: per-o f64 sum/sumsq -> partials[rb][2O].  PASS 1: BN+leaky+max_k -> out
template<int PASS, int C, int O>
__global__ __launch_bounds__(256, 2) void k_conv2(const float* __restrict__ x, int ld,
                                                  const int* __restrict__ idx,
                                                  const float* __restrict__ W,
                                                  const float* __restrict__ sbuf,
                                                  double* __restrict__ partials,
                                                  const float* __restrict__ ss,
                                                  float* __restrict__ out, int ldo) {
    constexpr int C4 = (C / 4 < 8) ? 8 : C / 4;
    __shared__ __align__(16) float smem[(80 + 64) * C4 * 4];
    __shared__ int sidx[80];
    float4* As = (float4*)smem;
    float4* Bs = (float4*)(smem + 80 * C4 * 4);

    const int tid = threadIdx.x;
    const int rb = blockIdx.x;            // 0..2047
    const int o0 = blockIdx.y * 64;
    const int p0 = rb * 8;                // 8 points per block (same batch: 8 | 2048)
    const int b = p0 >> 11;
    const float* xb = x + (size_t)b * NPT * ld;

    if (tid < 80) sidx[tid] = idx[p0 * KNN + tid];
    __syncthreads();

    for (int i = tid; i < 80 * C4; i += 256) {
        int r = i / C4, c4 = i - r * C4;
        float4 v = make_float4(0.f, 0.f, 0.f, 0.f);
        if (c4 * 4 < C) v = *(const float4*)(xb + (size_t)sidx[r] * ld + c4 * 4);
        As[r * C4 + (c4 ^ (r & 7))] = v;
    }
    for (int i = tid; i < 64 * C4; i += 256) {
        int oo = i / C4, c4 = i - oo * C4;
        float4 v = make_float4(0.f, 0.f, 0.f, 0.f);
        if (c4 * 4 < C) v = *(const float4*)(W + (size_t)(o0 + oo) * 2 * C + c4 * 4);
        Bs[oo * C4 + (c4 ^ (oo & 7))] = v;
    }
    __syncthreads();

    const int tx = tid & 15, ty = tid >> 4;
    const int o_l = tx * 4;
    float acc[5][4];
#pragma unroll
    for (int a = 0; a < 5; ++a)
#pragma unroll
        for (int c = 0; c < 4; ++c) acc[a][c] = 0.f;

    for (int c4 = 0; c4 < C4; ++c4) {
        float4 av[5], bv[4];
#pragma unroll
        for (int rj = 0; rj < 5; ++rj) { int r = ty * 5 + rj; av[rj] = As[r * C4 + (c4 ^ (r & 7))]; }
#pragma unroll
        for (int oj = 0; oj < 4; ++oj) { int oo = o_l + oj; bv[oj] = Bs[oo * C4 + (c4 ^ (oo & 7))]; }
#pragma unroll
        for (int rj = 0; rj < 5; ++rj)
#pragma unroll
            for (int oj = 0; oj < 4; ++oj) {
                acc[rj][oj] = fmaf(av[rj].x, bv[oj].x, acc[rj][oj]);
                acc[rj][oj] = fmaf(av[rj].y, bv[oj].y, acc[rj][oj]);
                acc[rj][oj] = fmaf(av[rj].z, bv[oj].z, acc[rj][oj]);
                acc[rj][oj] = fmaf(av[rj].w, bv[oj].w, acc[rj][oj]);
            }
    }

    // rows ty*5..ty*5+4 all belong to point pt = ty>>1 (k 0-4 for even ty, 5-9 odd)
    const int pt = ty >> 1;
    const float4 s4 = *(const float4*)(sbuf + (size_t)(p0 + pt) * O + o0 + o_l);
    const float* s4f = (const float*)&s4;

    if (PASS == 0) {
        double sum[4] = {0, 0, 0, 0}, sq[4] = {0, 0, 0, 0};
#pragma unroll
        for (int rj = 0; rj < 5; ++rj)
#pragma unroll
            for (int oj = 0; oj < 4; ++oj) {
                float hf = acc[rj][oj] + s4f[oj];
                double hd = (double)hf;
                sum[oj] += hd; sq[oj] += hd * hd;
            }
        __syncthreads();
        double* red = (double*)smem;   // [16][64][2] = 16 KB (smem >= 18 KB for all C)
#pragma unroll
        for (int oj = 0; oj < 4; ++oj) {
            red[(ty * 64 + o_l + oj) * 2 + 0] = sum[oj];
            red[(ty * 64 + o_l + oj) * 2 + 1] = sq[oj];
        }
        __syncthreads();
        if (tid < 128) {
            int o = tid & 63, w = tid >> 6;
            double a = 0.0;
            for (int t2 = 0; t2 < 16; ++t2) a += red[(t2 * 64 + o) * 2 + w];
            partials[(size_t)rb * 2 * O + (size_t)w * O + o0 + o] = a;
        }
    } else {
        float m4[4];
#pragma unroll
        for (int oj = 0; oj < 4; ++oj) {
            float sc = ss[o0 + o_l + oj], sh = ss[O + o0 + o_l + oj];
            float m = -FLT_MAX;
#pragma unroll
            for (int rj = 0; rj < 5; ++rj) {
                float h = (acc[rj][oj] + s4f[oj]) * sc + sh;
                h = h > 0.f ? h : 0.2f * h;
                m = fmaxf(m, h);
            }
            m4[oj] = m;
        }
        __syncthreads();
        float* red = smem;             // [16][64]
#pragma unroll
        for (int oj = 0; oj < 4; ++oj) red[ty * 64 + o_l + oj] = m4[oj];
        __syncthreads();
        if ((ty & 1) == 0) {
            float4 o4;
            float* po = (float*)&o4;
#pragma unroll
            for (int oj = 0; oj < 4; ++oj)
                po[oj] = fmaxf(red[ty * 64 + o_l + oj], red[(ty + 1) * 64 + o_l + oj]);
            *(float4*)(out + (size_t)(p0 + pt) * ldo + o0 + o_l) = o4;
        }
    }
}

// ---------------- BN finalize: deterministic fixed-order reduction ----------------
__global__ __launch_bounds__(256) void k_bnstats(const double* __restrict__ partials,
                                                 const float* __restrict__ g,
                                                 const float* __restrict__ be,
                                                 float* __restrict__ ss, int O) {
    int o = threadIdx.x;
    if (o >= O) return;
    double sum = 0.0, sq = 0.0;
    for (int b = 0; b < STAT_BLOCKS; ++b) {
        sum += partials[(size_t)b * 2 * O + o];
        sq  += partials[(size_t)b * 2 * O + O + o];
    }
    const double M = 163840.0;   // 8*2048*10
    double mu = sum / M;
    double var = sq / M - mu * mu;
    if (var < 0.0) var = 0.0;
    float scv = (float)((double)g[o] / sqrt(var + 1e-5));
    ss[o] = scv;
    ss[O + o] = be[o] - (float)mu * scv;
}

// ---------------- dense GEMM: 64x64 tile, BK=64, 4x4 acc/thread ----------------
// out[p][o] = act(in[p]·W[o] + bias)  (W row-major [Cout][Cin])
template<int ACT>
__global__ __launch_bounds__(256, 2) void k_dense2(const float* __restrict__ in, int ldi, int Cin,
                                                   const float* __restrict__ W,
                                                   const float* __restrict__ bias,
                                                   float* __restrict__ out, int ldo, int Cout) {
    __shared__ __align__(16) float smem[2 * 64 * 64];   // As + Bs, 32 KB
    float4* As = (float4*)smem;
    float4* Bs = (float4*)(smem + 64 * 64);
    const int tid = threadIdx.x;
    const int p0 = blockIdx.x * 64;
    const int o0 = blockIdx.y * 64;
    const int tx = tid & 15, ty = tid >> 4;

    float acc[4][4];
#pragma unroll
    for (int a = 0; a < 4; ++a)
#pragma unroll
        for (int b = 0; b < 4; ++b) acc[a][b] = 0.f;

    const int ntile = (Cin + 63) / 64;
    for (int kt = 0; kt < ntile; ++kt) {
        const int c0 = kt * 64;
        __syncthreads();   // protect previous tile reads
        for (int i = tid; i < 64 * 16; i += 256) {
            int r = i >> 4, c4 = i & 15;
            float4 v = make_float4(0.f, 0.f, 0.f, 0.f);
            if (c0 + c4 * 4 < Cin) v = *(const float4*)(in + (size_t)(p0 + r) * ldi + c0 + c4 * 4);
            As[r * 16 + (c4 ^ (r & 7))] = v;
        }
        for (int i = tid; i < 64 * 16; i += 256) {
            int oo = i >> 4, c4 = i & 15;
            float4 v = make_float4(0.f, 0.f, 0.f, 0.f);
            if (o0 + oo < Cout && c0 + c4 * 4 < Cin)
                v = *(const float4*)(W + (size_t)(o0 + oo) * Cin + c0 + c4 * 4);
            Bs[oo * 16 + (c4 ^ (oo & 7))] = v;
        }
        __syncthreads();
#pragma unroll
        for (int c4 = 0; c4 < 16; ++c4) {
            float4 av[4], bv[4];
#pragma unroll
            for (int rj = 0; rj < 4; ++rj) { int r = ty * 4 + rj; av[rj] = As[r * 16 + (c4 ^ (r & 7))]; }
#pragma unroll
            for (int oj = 0; oj < 4; ++oj) { int oo = tx * 4 + oj; bv[oj] = Bs[oo * 16 + (c4 ^ (oo & 7))]; }
#pragma unroll
            for (int rj = 0; rj < 4; ++rj)
#pragma unroll
                for (int oj = 0; oj < 4; ++oj) {
                    acc[rj][oj] = fmaf(av[rj].x, bv[oj].x, acc[rj][oj]);
                    acc[rj][oj] = fmaf(av[rj].y, bv[oj].y, acc[rj][oj]);
                    acc[rj][oj] = fmaf(av[rj].z, bv[oj].z, acc[rj][oj]);
                    acc[rj][oj] = fmaf(av[rj].w, bv[oj].w, acc[rj][oj]);
                }
        }
    }

    const int ob = o0 + tx * 4;
    float bv4[4] = {0.f, 0.f, 0.f, 0.f};
    if (bias) {
#pragma unroll
        for (int oj = 0; oj < 4; ++oj) if (ob + oj < Cout) bv4[oj] = bias[ob + oj];
    }
#pragma unroll
    for (int rj = 0; rj < 4; ++rj) {
        float v4[4];
#pragma unroll
        for (int oj = 0; oj < 4; ++oj) {
            float v = acc[rj][oj] + bv4[oj];
            if (ACT) v = v > 0.f ? v : 0.2f * v;
            v4[oj] = v;
        }
        float* orow = out + (size_t)(p0 + ty * 4 + rj) * ldo;
        if (ob + 3 < Cout) {
            *(float4*)(orow + ob) = make_float4(v4[0], v4[1], v4[2], v4[3]);
        } else {
#pragma unroll
            for (int oj = 0; oj < 4; ++oj) if (ob + oj < Cout) orow[ob + oj] = v4[oj];
        }
    }
}

extern "C" void kernel_launch(void* const* d_in, const int* in_sizes, int n_in,
                              void* d_out, int out_size, void* d_ws, size_t ws_size,
                              hipStream_t stream) {
    const float* x   = (const float*)d_in[0];
    const float* W1  = (const float*)d_in[1];
    const float* g1  = (const float*)d_in[2];
    const float* b1  = (const float*)d_in[3];
    const float* W2  = (const float*)d_in[4];
    const float* g2  = (const float*)d_in[5];
    const float* b2  = (const float*)d_in[6];
    const float* W3  = (const float*)d_in[7];
    const float* g3  = (const float*)d_in[8];
    const float* b3  = (const float*)d_in[9];
    const float* W4  = (const float*)d_in[10];
    const float* g4  = (const float*)d_in[11];
    const float* b4  = (const float*)d_in[12];
    const float* W5  = (const float*)d_in[13];
    const float* W6  = (const float*)d_in[14];
    const float* Wd1 = (const float*)d_in[15];
    const float* bd1 = (const float*)d_in[16];
    const float* Wd2 = (const float*)d_in[17];
    const float* bd2 = (const float*)d_in[18];

    char* ws = (char*)d_ws;
    float* cat    = (float*)(ws);                 // [0, 33,554,432)
    double* norms = (double*)(ws + 33554432);     // 131,072 B
    float* qT     = (float*)(ws + 33685504);      // 8,388,608 B (knn phase)
    double* pk    = (double*)(ws + 42074112);     // 10,485,760 B (knn phase)
    int*   pi     = (int*)  (ws + 52559872);      // 5,242,880 B (knn phase)
    float* pts    = (float*)(ws + 57802752);      // 1,572,864 B (layer-1 input)
    int*   idx    = (int*)  (ws + 59375616);      // 655,360 B
    float* ssb    = (float*)(ws + 60030976);      // 1024 f32
    float* sbuf   = (float*)(ws + 33685504);      // <=16.8 MB, overlays qT+pk (conv phase)
    double* parts = (double*)(ws + 50462720);     // <=8.4 MB, overlays pk tail/pi/pts(L4 only)
    float* h5     = (float*)(ws + 33554432);      // tail only
    float* tmp    = (float*)(ws);                 // tail only, overlays dead cat

    float* feat = (float*)d_out;                // 16384 x 552
    float* logi = (float*)d_out + 9043968;      // 16384 x 255

    dim3 blk(256);
    dim3 kgrid(NCHUNK, 64);

    k_pts<<<dim3((NPTS_TOTAL * 24 + 255) / 256), blk, 0, stream>>>(x, pts);

    // ---- layer 1: C=24, O=64 ----
    k_prep<<<dim3(64), blk, 0, stream>>>(pts, 24, 24, norms, qT);
    k_knn2<24><<<kgrid, blk, 0, stream>>>(pts, 24, norms, qT, pk, pi);
    k_kmerge<<<dim3(64), blk, 0, stream>>>(pk, pi, idx);
    k_sgemm<24, 64><<<dim3(256, 1), blk, 0, stream>>>(pts, 24, W1, sbuf);
    k_conv2<0, 24, 64><<<dim3(STAT_BLOCKS, 1), blk, 0, stream>>>(pts, 24, idx, W1, sbuf, parts, nullptr, nullptr, 0);
    k_bnstats<<<dim3(1), blk, 0, stream>>>(parts, g1, b1, ssb, 64);
    k_conv2<1, 24, 64><<<dim3(STAT_BLOCKS, 1), blk, 0, stream>>>(pts, 24, idx, W1, sbuf, nullptr, ssb, cat + 0, 512);

    // ---- layer 2: C=64, O=64 ----
    k_prep<<<dim3(64), blk, 0, stream>>>(cat + 0, 512, 64, norms, qT);
    k_knn2<64><<<kgrid, blk, 0, stream>>>(cat + 0, 512, norms, qT, pk, pi);
    k_kmerge<<<dim3(64), blk, 0, stream>>>(pk, pi, idx);
    k_sgemm<64, 64><<<dim3(256, 1), blk, 0, stream>>>(cat + 0, 512, W2, sbuf);
    k_conv2<0, 64, 64><<<dim3(STAT_BLOCKS, 1), blk, 0, stream>>>(cat + 0, 512, idx, W2, sbuf, parts, nullptr, nullptr, 0);
    k_bnstats<<<dim3(1), blk, 0, stream>>>(parts, g2, b2, ssb, 64);
    k_conv2<1, 64, 64><<<dim3(STAT_BLOCKS, 1), blk, 0, stream>>>(cat + 0, 512, idx, W2, sbuf, nullptr, ssb, cat + 64, 512);

    // ---- layer 3: C=64, O=128 ----
    k_prep<<<dim3(64), blk, 0, stream>>>(cat + 64, 512, 64, norms, qT);
    k_knn2<64><<<kgrid, blk, 0, stream>>>(cat + 64, 512, norms, qT, pk, pi);
    k_kmerge<<<dim3(64), blk, 0, stream>>>(pk, pi, idx);
    k_sgemm<64, 128><<<dim3(256, 2), blk, 0, stream>>>(cat + 64, 512, W3, sbuf);
    k_conv2<0, 64, 128><<<dim3(STAT_BLOCKS, 2), blk, 0, stream>>>(cat + 64, 512, idx, W3, sbuf, parts, nullptr, nullptr, 0);
    k_bnstats<<<dim3(1), blk, 0, stream>>>(parts, g3, b3, ssb, 128);
    k_conv2<1, 64, 128><<<dim3(STAT_BLOCKS, 2), blk, 0, stream>>>(cat + 64, 512, idx, W3, sbuf, nullptr, ssb, cat + 128, 512);

    // ---- layer 4: C=128, O=256 ----
    k_prep<<<dim3(64), blk, 0, stream>>>(cat + 128, 512, 128, norms, qT);
    k_knn2<128><<<kgrid, blk, 0, stream>>>(cat + 128, 512, norms, qT, pk, pi);
    k_kmerge<<<dim3(64), blk, 0, stream>>>(pk, pi, idx);
    k_sgemm<128, 256><<<dim3(256, 4), blk, 0, stream>>>(cat + 128, 512, W4, sbuf);
    k_conv2<0, 128, 256><<<dim3(STAT_BLOCKS, 4), blk, 0, stream>>>(cat + 128, 512, idx, W4, sbuf, parts, nullptr, nullptr, 0);
    k_bnstats<<<dim3(1), blk, 0, stream>>>(parts, g4, b4, ssb, 256);
    k_conv2<1, 128, 256><<<dim3(STAT_BLOCKS, 4), blk, 0, stream>>>(cat + 128, 512, idx, W4, sbuf, nullptr, ssb, cat + 256, 512);

    // ---- tail: register-blocked GEMMs ----
    k_dense2<1><<<dim3(256, 4), blk, 0, stream>>>(cat, 512, 512, W5, nullptr, h5, 256, 256);
    k_dense2<1><<<dim3(256, 9), blk, 0, stream>>>(h5, 256, 256, W6, nullptr, feat, 552, 552);
    k_dense2<0><<<dim3(256, 9), blk, 0, stream>>>(feat, 552, 552, Wd1, bd1, tmp, 552, 552);
    k_dense2<0><<<dim3(256, 4), blk, 0, stream>>>(tmp, 552, 552, Wd2, bd2, logi, 255, 255);
}